// Round 11
// baseline (398.971 us; speedup 1.0000x reference)
//
#include <hip/hip_runtime.h>
#include <hip/hip_bf16.h>

#define N_NODES   100000
#define N_EDGES   1000000
#define N_FEAT    136
#define HIDDEN    64
#define N_CLASSES 2
#define NUM_GRAPHS 512

#define NP_PAD    100352          // 98 * 1024
#define SCAN_BLKS 98

#define CHUNK      16
#define NCHUNK     (N_EDGES / CHUNK)   // 62500 exact
#define SEG_BLOCKS 2048                // 8192 waves = 32/CU capacity

#define XCD        8
#define PART_N     (N_NODES / XCD)     // 12500 exact

#define K1_4 (N_FEAT / 4)              // 34
#define K2_4 (HIDDEN / 4)              // 16

typedef unsigned short ushort_t;

// fp32 -> bf16 (RTNE), bf16 -> fp32
__device__ __forceinline__ ushort_t f2b(float v) {
    unsigned b = __float_as_uint(v);
    return (ushort_t)((b + 0x7FFF + ((b >> 16) & 1)) >> 16);
}
__device__ __forceinline__ float b2f(ushort_t u) {
    return __uint_as_float(((unsigned)u) << 16);
}
__device__ __forceinline__ unsigned pack2(float a, float b) {
    return (unsigned)f2b(a) | ((unsigned)f2b(b) << 16);
}

// ============================ CSR build =====================================
__global__ __launch_bounds__(256) void hist_kernel(const int* __restrict__ dst,
                                                   int* __restrict__ cnt) {
    int e = blockIdx.x * 256 + threadIdx.x;
    if (e < N_EDGES) atomicAdd(&cnt[dst[e]], 1);
}

__global__ __launch_bounds__(256) void scan1_kernel(const int* __restrict__ cnt,
                                                    int* __restrict__ row_ptr,
                                                    int* __restrict__ partials) {
    __shared__ int sd[256];
    int b = blockIdx.x, t = threadIdx.x;
    int i0 = b * 1024 + t * 4;
    int c0 = (i0 + 0 < N_NODES) ? cnt[i0 + 0] : 0;
    int c1 = (i0 + 1 < N_NODES) ? cnt[i0 + 1] : 0;
    int c2 = (i0 + 2 < N_NODES) ? cnt[i0 + 2] : 0;
    int c3 = (i0 + 3 < N_NODES) ? cnt[i0 + 3] : 0;
    int tsum = c0 + c1 + c2 + c3;
    sd[t] = tsum;
    __syncthreads();
    for (int off = 1; off < 256; off <<= 1) {
        int v = (t >= off) ? sd[t - off] : 0;
        __syncthreads();
        sd[t] += v;
        __syncthreads();
    }
    int excl = sd[t] - tsum;
    row_ptr[i0 + 0] = excl;
    row_ptr[i0 + 1] = excl + c0;
    row_ptr[i0 + 2] = excl + c0 + c1;
    row_ptr[i0 + 3] = excl + c0 + c1 + c2;
    if (t == 255) partials[b] = sd[255];
}

__global__ __launch_bounds__(128) void scan2_kernel(int* __restrict__ partials) {
    __shared__ int sd[128];
    int t = threadIdx.x;
    int v = (t < SCAN_BLKS) ? partials[t] : 0;
    sd[t] = v;
    __syncthreads();
    for (int off = 1; off < 128; off <<= 1) {
        int u = (t >= off) ? sd[t - off] : 0;
        __syncthreads();
        sd[t] += u;
        __syncthreads();
    }
    partials[t] = sd[t] - v;
}

__global__ __launch_bounds__(256) void scan3_kernel(int* __restrict__ row_ptr,
                                                    int* __restrict__ cursor,
                                                    const int* __restrict__ partials) {
    int i = blockIdx.x * 256 + threadIdx.x;
    if (i < N_NODES) {
        int v = row_ptr[i] + partials[i >> 10];
        row_ptr[i] = v;
        cursor[i]  = v;
    }
    if (i == N_NODES) row_ptr[N_NODES] = N_EDGES;
}

// XCD-partitioned scatter: partition p (= blockIdx&7) handles dst range
// [p*12500,(p+1)*12500) -> each csr_src line written by one XCD only.
__global__ __launch_bounds__(256) void scatter_kernel(const int* __restrict__ src,
                                                      const int* __restrict__ dst,
                                                      int* __restrict__ cursor,
                                                      int* __restrict__ csr_src) {
    int part = blockIdx.x & (XCD - 1);
    int e = (blockIdx.x >> 3) * 256 + threadIdx.x;
    if (e >= N_EDGES) return;
    int d = dst[e];
    int lo = part * PART_N;
    if (d >= lo && d < lo + PART_N) {
        int pos = atomicAdd(&cursor[d], 1);
        csr_src[pos] = src[e];
    }
}

// coalesced expansion: dst_sorted[row_ptr[i]..row_ptr[i+1]) = i
__global__ __launch_bounds__(256) void expand_kernel(const int* __restrict__ row_ptr,
                                                     int* __restrict__ dst_sorted) {
    int i = blockIdx.x * 256 + threadIdx.x;
    if (i < N_NODES) {
        int s = row_ptr[i], e = row_ptr[i + 1];
        for (int j = s; j < e; ++j) dst_sorted[j] = i;
    }
}

__global__ __launch_bounds__(256) void dinv_kernel(const int* __restrict__ row_ptr,
                                                   float* __restrict__ dinv) {
    int i = blockIdx.x * 256 + threadIdx.x;
    if (i < N_NODES)
        dinv[i] = rsqrtf((float)(row_ptr[i + 1] - row_ptr[i] + 1));  // +1 self-loop
}

// ---- graph boundaries: gstart[g] = lower_bound(batch, g) -------------------
__global__ __launch_bounds__(256) void gbounds_kernel(const int* __restrict__ batch,
                                                      int* __restrict__ gstart) {
    int g = blockIdx.x * 256 + threadIdx.x;
    if (g > NUM_GRAPHS) return;
    int lo = 0, hi = N_NODES;
    while (lo < hi) {
        int mid = (lo + hi) >> 1;
        if (batch[mid] < g) lo = mid + 1; else hi = mid;
    }
    gstart[g] = lo;
}

// ==================== t' = (x @ W1) * dinv -> bf16  (136 -> 64) =============
// 64-node tile; x AND W1 staged as packed bf16 in LDS (34.8 KB -> 4 blk/CU);
// thread = 8 nodes x 2 adjacent f.
__global__ __launch_bounds__(256) void mm1_kernel(const float* __restrict__ x,
                                                  const float* __restrict__ W1,
                                                  const float* __restrict__ dinv,
                                                  ushort_t* __restrict__ tpb) {
    __shared__ unsigned wsb[N_FEAT * HIDDEN / 2]; // bf16x2 [k][fg], 17408 B
    __shared__ unsigned xsb[64 * (N_FEAT / 2)];   // bf16x2, 17408 B
    int t = threadIdx.x;
    int n0 = blockIdx.x * 64;
    {
        const float2* W12 = (const float2*)W1;
        for (int i = t; i < N_FEAT * HIDDEN / 2; i += 256) {
            float2 v = W12[i];
            wsb[i] = pack2(v.x, v.y);
        }
        const float4* x4 = (const float4*)x;
        for (int i = t; i < 64 * K1_4; i += 256) {
            int r = i / K1_4, c = i % K1_4;
            int n = n0 + r; if (n >= N_NODES) n = N_NODES - 1;
            float4 v = x4[(long long)n * K1_4 + c];
            xsb[r * (N_FEAT / 2) + 2 * c]     = pack2(v.x, v.y);
            xsb[r * (N_FEAT / 2) + 2 * c + 1] = pack2(v.z, v.w);
        }
    }
    __syncthreads();
    int fg = t & 31;     // f = 2fg, 2fg+1
    int ng = t >> 5;     // nodes ng + 8j
    float acc0[8], acc1[8];
#pragma unroll
    for (int j = 0; j < 8; ++j) { acc0[j] = 0.f; acc1[j] = 0.f; }
    for (int k4 = 0; k4 < K1_4; ++k4) {
        unsigned uw0 = wsb[(4 * k4 + 0) * 32 + fg];
        unsigned uw1 = wsb[(4 * k4 + 1) * 32 + fg];
        unsigned uw2 = wsb[(4 * k4 + 2) * 32 + fg];
        unsigned uw3 = wsb[(4 * k4 + 3) * 32 + fg];
        float w0x = __uint_as_float(uw0 << 16), w0y = __uint_as_float(uw0 & 0xffff0000u);
        float w1x = __uint_as_float(uw1 << 16), w1y = __uint_as_float(uw1 & 0xffff0000u);
        float w2x = __uint_as_float(uw2 << 16), w2y = __uint_as_float(uw2 & 0xffff0000u);
        float w3x = __uint_as_float(uw3 << 16), w3y = __uint_as_float(uw3 & 0xffff0000u);
#pragma unroll
        for (int j = 0; j < 8; ++j) {
            uint2 u = *(const uint2*)&xsb[(ng + 8 * j) * (N_FEAT / 2) + 2 * k4];
            float vx = __uint_as_float(u.x << 16);
            float vy = __uint_as_float(u.x & 0xffff0000u);
            float vz = __uint_as_float(u.y << 16);
            float vw = __uint_as_float(u.y & 0xffff0000u);
            acc0[j] += vx * w0x + vy * w1x + vz * w2x + vw * w3x;
            acc1[j] += vx * w0y + vy * w1y + vz * w2y + vw * w3y;
        }
    }
#pragma unroll
    for (int j = 0; j < 8; ++j) {
        int n = n0 + ng + 8 * j;
        if (n < N_NODES) {
            float di = dinv[n];
            ((unsigned*)tpb)[n * 32 + fg] = pack2(acc0[j] * di, acc1[j] * di);
        }
    }
}

// ==================== t' = (h @ W2) * dinv -> bf16  (64 -> 64) ==============
__global__ __launch_bounds__(256) void mm2_kernel(const float* __restrict__ h,
                                                  const float* __restrict__ W2,
                                                  const float* __restrict__ dinv,
                                                  ushort_t* __restrict__ tpb) {
    __shared__ unsigned wsb[HIDDEN * HIDDEN / 2]; // bf16x2, 8192 B
    __shared__ unsigned hsb[64 * (HIDDEN / 2)];   // bf16x2, 8192 B
    int t = threadIdx.x;
    int n0 = blockIdx.x * 64;
    {
        const float2* W22 = (const float2*)W2;
        for (int i = t; i < HIDDEN * HIDDEN / 2; i += 256) {
            float2 v = W22[i];
            wsb[i] = pack2(v.x, v.y);
        }
        const float4* h4 = (const float4*)h;
        for (int i = t; i < 64 * K2_4; i += 256) {
            int r = i / K2_4, c = i % K2_4;
            int n = n0 + r; if (n >= N_NODES) n = N_NODES - 1;
            float4 v = h4[(long long)n * K2_4 + c];
            hsb[r * (HIDDEN / 2) + 2 * c]     = pack2(v.x, v.y);
            hsb[r * (HIDDEN / 2) + 2 * c + 1] = pack2(v.z, v.w);
        }
    }
    __syncthreads();
    int fg = t & 31;
    int ng = t >> 5;
    float acc0[8], acc1[8];
#pragma unroll
    for (int j = 0; j < 8; ++j) { acc0[j] = 0.f; acc1[j] = 0.f; }
    for (int k4 = 0; k4 < K2_4; ++k4) {
        unsigned uw0 = wsb[(4 * k4 + 0) * 32 + fg];
        unsigned uw1 = wsb[(4 * k4 + 1) * 32 + fg];
        unsigned uw2 = wsb[(4 * k4 + 2) * 32 + fg];
        unsigned uw3 = wsb[(4 * k4 + 3) * 32 + fg];
        float w0x = __uint_as_float(uw0 << 16), w0y = __uint_as_float(uw0 & 0xffff0000u);
        float w1x = __uint_as_float(uw1 << 16), w1y = __uint_as_float(uw1 & 0xffff0000u);
        float w2x = __uint_as_float(uw2 << 16), w2y = __uint_as_float(uw2 & 0xffff0000u);
        float w3x = __uint_as_float(uw3 << 16), w3y = __uint_as_float(uw3 & 0xffff0000u);
#pragma unroll
        for (int j = 0; j < 8; ++j) {
            uint2 u = *(const uint2*)&hsb[(ng + 8 * j) * (HIDDEN / 2) + 2 * k4];
            float vx = __uint_as_float(u.x << 16);
            float vy = __uint_as_float(u.x & 0xffff0000u);
            float vz = __uint_as_float(u.y << 16);
            float vw = __uint_as_float(u.y & 0xffff0000u);
            acc0[j] += vx * w0x + vy * w1x + vz * w2x + vw * w3x;
            acc1[j] += vx * w0y + vy * w1y + vz * w2y + vw * w3y;
        }
    }
#pragma unroll
    for (int j = 0; j < 8; ++j) {
        int n = n0 + ng + 8 * j;
        if (n < N_NODES) {
            float di = dinv[n];
            ((unsigned*)tpb)[n * 32 + fg] = pack2(acc0[j] * di, acc1[j] * di);
        }
    }
}

// ======== edge-parallel segmented reduce over CSR (dst-sorted) ==============
__global__ __launch_bounds__(256, 4) void edge_seg_kernel(const int* __restrict__ csr_src,
                                                          const int* __restrict__ dst_sorted,
                                                          const ushort_t* __restrict__ tpb,
                                                          float* __restrict__ agg) {
    int lane = threadIdx.x & 63;
    int wid  = (blockIdx.x * 256 + threadIdx.x) >> 6;
    const int nw = SEG_BLOCKS * 4;               // 8192 waves
    int i16 = lane & 15;

    int sv = csr_src[wid * CHUNK + i16];
    int dv = dst_sorted[wid * CHUNK + i16];
    for (int c = wid; c < NCHUNK; c += nw) {
        int cn = c + nw;
        int sv_next = sv, dv_next = dv;
        if (cn < NCHUNK) {                        // prefetch next chunk's indices
            sv_next = csr_src[cn * CHUNK + i16];
            dv_next = dst_sorted[cn * CHUNK + i16];
        }

        float vv[CHUNK];
        int dd[CHUNK];
#pragma unroll
        for (int j = 0; j < CHUNK; ++j) {
            int s = __builtin_amdgcn_readlane(sv, j);          // scalar src
            dd[j] = __builtin_amdgcn_readlane(dv, j);          // scalar dst
            vv[j] = b2f(tpb[s * 64 + lane]);                   // independent gather
        }
        float acc = vv[0];
        int dprev = dd[0];
#pragma unroll
        for (int j = 1; j < CHUNK; ++j) {
            if (dd[j] != dprev) {                // wave-uniform branch
                atomicAdd(&agg[dprev * 64 + lane], acc);
                acc = 0.0f;
                dprev = dd[j];
            }
            acc += vv[j];
        }
        atomicAdd(&agg[dprev * 64 + lane], acc);
        sv = sv_next; dv = dv_next;
    }
}

// ---- epilogue 1: h = relu((agg + self) * dinv + b) -------------------------
__global__ __launch_bounds__(256) void epi1_kernel(const float* __restrict__ agg,
                                                   const ushort_t* __restrict__ tpb,
                                                   const float* __restrict__ dinv,
                                                   const float* __restrict__ bias,
                                                   float* __restrict__ h) {
    int idx = blockIdx.x * 256 + threadIdx.x;    // 25000 blocks exact
    int n = idx >> 6, f = idx & 63;
    float v = fmaf(agg[idx] + b2f(tpb[idx]), dinv[n], bias[f]);
    h[idx] = fmaxf(v, 0.0f);
}

// ---- layer-2 epilogue + pool: one BLOCK per graph (4 waves), no atomics ----
__global__ __launch_bounds__(256) void gpool_kernel(const float* __restrict__ agg,
                                                    const ushort_t* __restrict__ tpb,
                                                    const float* __restrict__ dinv,
                                                    const float* __restrict__ bias,
                                                    const int* __restrict__ gstart,
                                                    float* __restrict__ sums,
                                                    float* __restrict__ gcount) {
    __shared__ float red[4][64];
    int lane = threadIdx.x & 63;
    int w = threadIdx.x >> 6;
    int g = blockIdx.x;                      // 512 blocks
    int s = gstart[g], e = gstart[g + 1];
    float b = bias[lane];
    float acc = 0.0f;
    for (int n = s + w; n < e; n += 4) {
        int idx = n * 64 + lane;
        acc += fmaxf(fmaf(agg[idx] + b2f(tpb[idx]), dinv[n], b), 0.0f);
    }
    red[w][lane] = acc;
    __syncthreads();
    if (threadIdx.x < 64) {
        float tot = red[0][lane] + red[1][lane] + red[2][lane] + red[3][lane];
        sums[g * 64 + lane] = tot;
        if (lane == 0) gcount[g] = (float)(e - s);
    }
}

// ---- head: out = (sums/counts) @ Wout + bout -------------------------------
__global__ __launch_bounds__(256) void out_kernel(const float* __restrict__ sums,
                                                  const float* __restrict__ gcount,
                                                  const float* __restrict__ Wout,
                                                  const float* __restrict__ bout,
                                                  float* __restrict__ out) {
    int idx = blockIdx.x * 256 + threadIdx.x;
    if (idx >= NUM_GRAPHS * N_CLASSES) return;
    int g = idx / N_CLASSES, c = idx % N_CLASSES;
    float inv_cnt = 1.0f / fmaxf(gcount[g], 1.0f);
    float acc = 0.0f;
#pragma unroll
    for (int k = 0; k < HIDDEN; ++k)
        acc += sums[g * HIDDEN + k] * Wout[k * N_CLASSES + c];
    out[idx] = acc * inv_cnt + bout[c];
}

extern "C" void kernel_launch(void* const* d_in, const int* in_sizes, int n_in,
                              void* d_out, int out_size, void* d_ws, size_t ws_size,
                              hipStream_t stream) {
    const float* x     = (const float*)d_in[0];
    const int*   ei    = (const int*)d_in[1];
    const int*   batch = (const int*)d_in[2];
    const float* W1    = (const float*)d_in[3];
    const float* b1    = (const float*)d_in[4];
    const float* W2    = (const float*)d_in[5];
    const float* b2    = (const float*)d_in[6];
    const float* Wout  = (const float*)d_in[7];
    const float* bout  = (const float*)d_in[8];
    float* out = (float*)d_out;

    const int* src = ei;
    const int* dst = ei + N_EDGES;

    // -------- workspace layout (~73.5 MB) --------
    char* p = (char*)d_ws;
    int*      row_ptr   = (int*)p;      p += (NP_PAD + 256) * sizeof(int);
    int*      cnt       = (int*)p;      p += NP_PAD * sizeof(int);   // hist, then cursor
    int*      partials  = (int*)p;      p += 256 * sizeof(int);
    int*      gstart    = (int*)p;      p += (NUM_GRAPHS + 64) * sizeof(int);
    int*      csr_src   = (int*)p;      p += (size_t)N_EDGES * sizeof(int);   // 4 MB
    int*      dst_sorted= (int*)p;      p += (size_t)N_EDGES * sizeof(int);   // 4 MB
    float*    dinv      = (float*)p;    p += NP_PAD * sizeof(float);
    ushort_t* tpb       = (ushort_t*)p; p += (size_t)N_NODES * HIDDEN * sizeof(ushort_t);
    float*    hbuf      = (float*)p;    p += (size_t)N_NODES * HIDDEN * sizeof(float);
    float*    agg       = (float*)p;    p += (size_t)N_NODES * HIDDEN * sizeof(float);
    float*    sums      = (float*)p;    p += NUM_GRAPHS * HIDDEN * sizeof(float);
    float*    gcount    = (float*)p;    p += NUM_GRAPHS * sizeof(float);

    const int NB_E  = (N_EDGES + 255) / 256;
    const int NB_N  = (N_NODES + 255) / 256;
    const int NB_MM = (N_NODES + 63) / 64;    // 1563 (last block guarded)
    const int NB_EP = N_NODES * HIDDEN / 256; // 25000 exact

    // -------- CSR build + graph bounds --------
    hipMemsetAsync(cnt, 0, NP_PAD * sizeof(int), stream);
    hist_kernel<<<NB_E, 256, 0, stream>>>(dst, cnt);
    scan1_kernel<<<SCAN_BLKS, 256, 0, stream>>>(cnt, row_ptr, partials);
    scan2_kernel<<<1, 128, 0, stream>>>(partials);
    scan3_kernel<<<NP_PAD / 256, 256, 0, stream>>>(row_ptr, cnt, partials);
    scatter_kernel<<<XCD * NB_E, 256, 0, stream>>>(src, dst, cnt, csr_src);
    expand_kernel<<<NB_N, 256, 0, stream>>>(row_ptr, dst_sorted);
    dinv_kernel<<<NB_N, 256, 0, stream>>>(row_ptr, dinv);
    gbounds_kernel<<<3, 256, 0, stream>>>(batch, gstart);

    hipMemsetAsync(agg, 0, (size_t)N_NODES * HIDDEN * sizeof(float), stream);

    // -------- layer 1 --------
    mm1_kernel<<<NB_MM, 256, 0, stream>>>(x, W1, dinv, tpb);
    edge_seg_kernel<<<SEG_BLOCKS, 256, 0, stream>>>(csr_src, dst_sorted, tpb, agg);
    epi1_kernel<<<NB_EP, 256, 0, stream>>>(agg, tpb, dinv, b1, hbuf);

    // -------- layer 2 (epilogue + pool fused, no atomics) --------
    mm2_kernel<<<NB_MM, 256, 0, stream>>>(hbuf, W2, dinv, tpb);
    hipMemsetAsync(agg, 0, (size_t)N_NODES * HIDDEN * sizeof(float), stream);
    edge_seg_kernel<<<SEG_BLOCKS, 256, 0, stream>>>(csr_src, dst_sorted, tpb, agg);
    gpool_kernel<<<NUM_GRAPHS, 256, 0, stream>>>(agg, tpb, dinv, b2, gstart,
                                                 sums, gcount);

    // -------- head --------
    out_kernel<<<(NUM_GRAPHS * N_CLASSES + 255) / 256, 256, 0, stream>>>(
        sums, gcount, Wout, bout, out);
}

// Round 12
// 356.690 us; speedup vs baseline: 1.1185x; 1.1185x over previous
//
#include <hip/hip_runtime.h>
#include <hip/hip_bf16.h>

#define N_NODES   100000
#define N_EDGES   1000000
#define N_FEAT    136
#define HIDDEN    64
#define N_CLASSES 2
#define NUM_GRAPHS 512

#define NP_PAD    100352          // 98 * 1024
#define SCAN_BLKS 98

#define CHUNK      16
#define NCHUNK     (N_EDGES / CHUNK)   // 62500 exact
#define SEG_BLOCKS 2048                // 8192 waves = 32/CU capacity

#define XCD        8
#define PART_N     (N_NODES / XCD)     // 12500 exact

#define K1_4 (N_FEAT / 4)              // 34
#define K2_4 (HIDDEN / 4)              // 16

#define K1PAD 160                      // 136 padded to 5*32, row stride (u16)
#define K2PAD 72                       // 64 + 8 pad to break bank alias

typedef unsigned short ushort_t;
typedef __attribute__((ext_vector_type(8))) short bf16x8;   // MFMA A/B frag
typedef __attribute__((ext_vector_type(4))) float f32x4;    // MFMA C/D frag

// fp32 -> bf16 (RTNE), bf16 -> fp32
__device__ __forceinline__ ushort_t f2b(float v) {
    unsigned b = __float_as_uint(v);
    return (ushort_t)((b + 0x7FFF + ((b >> 16) & 1)) >> 16);
}
__device__ __forceinline__ float b2f(ushort_t u) {
    return __uint_as_float(((unsigned)u) << 16);
}
__device__ __forceinline__ unsigned pack2(float a, float b) {
    return (unsigned)f2b(a) | ((unsigned)f2b(b) << 16);
}

// ============================ CSR build =====================================
__global__ __launch_bounds__(256) void hist_kernel(const int* __restrict__ dst,
                                                   int* __restrict__ cnt) {
    int e = blockIdx.x * 256 + threadIdx.x;
    if (e < N_EDGES) atomicAdd(&cnt[dst[e]], 1);
}

__global__ __launch_bounds__(256) void scan1_kernel(const int* __restrict__ cnt,
                                                    int* __restrict__ row_ptr,
                                                    int* __restrict__ partials) {
    __shared__ int sd[256];
    int b = blockIdx.x, t = threadIdx.x;
    int i0 = b * 1024 + t * 4;
    int c0 = (i0 + 0 < N_NODES) ? cnt[i0 + 0] : 0;
    int c1 = (i0 + 1 < N_NODES) ? cnt[i0 + 1] : 0;
    int c2 = (i0 + 2 < N_NODES) ? cnt[i0 + 2] : 0;
    int c3 = (i0 + 3 < N_NODES) ? cnt[i0 + 3] : 0;
    int tsum = c0 + c1 + c2 + c3;
    sd[t] = tsum;
    __syncthreads();
    for (int off = 1; off < 256; off <<= 1) {
        int v = (t >= off) ? sd[t - off] : 0;
        __syncthreads();
        sd[t] += v;
        __syncthreads();
    }
    int excl = sd[t] - tsum;
    row_ptr[i0 + 0] = excl;
    row_ptr[i0 + 1] = excl + c0;
    row_ptr[i0 + 2] = excl + c0 + c1;
    row_ptr[i0 + 3] = excl + c0 + c1 + c2;
    if (t == 255) partials[b] = sd[255];
}

__global__ __launch_bounds__(128) void scan2_kernel(int* __restrict__ partials) {
    __shared__ int sd[128];
    int t = threadIdx.x;
    int v = (t < SCAN_BLKS) ? partials[t] : 0;
    sd[t] = v;
    __syncthreads();
    for (int off = 1; off < 128; off <<= 1) {
        int u = (t >= off) ? sd[t - off] : 0;
        __syncthreads();
        sd[t] += u;
        __syncthreads();
    }
    partials[t] = sd[t] - v;
}

__global__ __launch_bounds__(256) void scan3_kernel(int* __restrict__ row_ptr,
                                                    int* __restrict__ cursor,
                                                    const int* __restrict__ partials) {
    int i = blockIdx.x * 256 + threadIdx.x;
    if (i < N_NODES) {
        int v = row_ptr[i] + partials[i >> 10];
        row_ptr[i] = v;
        cursor[i]  = v;
    }
    if (i == N_NODES) row_ptr[N_NODES] = N_EDGES;
}

// XCD-partitioned scatter: partition p (= blockIdx&7) handles dst range
// [p*12500,(p+1)*12500) -> each csr_src line written by one XCD only.
__global__ __launch_bounds__(256) void scatter_kernel(const int* __restrict__ src,
                                                      const int* __restrict__ dst,
                                                      int* __restrict__ cursor,
                                                      int* __restrict__ csr_src) {
    int part = blockIdx.x & (XCD - 1);
    int e = (blockIdx.x >> 3) * 256 + threadIdx.x;
    if (e >= N_EDGES) return;
    int d = dst[e];
    int lo = part * PART_N;
    if (d >= lo && d < lo + PART_N) {
        int pos = atomicAdd(&cursor[d], 1);
        csr_src[pos] = src[e];
    }
}

// coalesced expansion: dst_sorted[row_ptr[i]..row_ptr[i+1]) = i
__global__ __launch_bounds__(256) void expand_kernel(const int* __restrict__ row_ptr,
                                                     int* __restrict__ dst_sorted) {
    int i = blockIdx.x * 256 + threadIdx.x;
    if (i < N_NODES) {
        int s = row_ptr[i], e = row_ptr[i + 1];
        for (int j = s; j < e; ++j) dst_sorted[j] = i;
    }
}

__global__ __launch_bounds__(256) void dinv_kernel(const int* __restrict__ row_ptr,
                                                   float* __restrict__ dinv) {
    int i = blockIdx.x * 256 + threadIdx.x;
    if (i < N_NODES)
        dinv[i] = rsqrtf((float)(row_ptr[i + 1] - row_ptr[i] + 1));  // +1 self-loop
}

// ---- graph boundaries: gstart[g] = lower_bound(batch, g) -------------------
__global__ __launch_bounds__(256) void gbounds_kernel(const int* __restrict__ batch,
                                                      int* __restrict__ gstart) {
    int g = blockIdx.x * 256 + threadIdx.x;
    if (g > NUM_GRAPHS) return;
    int lo = 0, hi = N_NODES;
    while (lo < hi) {
        int mid = (lo + hi) >> 1;
        if (batch[mid] < g) lo = mid + 1; else hi = mid;
    }
    gstart[g] = lo;
}

// ========== MFMA mm1: t' = (x @ W1) * dinv -> bf16  (136 -> 64) =============
// block = 64 nodes (4 waves x 16), N=64, K padded to 160.
// A-frag: A[m=lane&15][k=quad*8+j]; B-frag from W_T[n][k]; C/D: row=quad*4+r.
__global__ __launch_bounds__(256) void mm1_kernel(const float* __restrict__ x,
                                                  const float* __restrict__ W1,
                                                  const float* __restrict__ dinv,
                                                  ushort_t* __restrict__ tpb) {
    __shared__ ushort_t xsb[64 * K1PAD];   // 20480 B, node-major bf16
    __shared__ ushort_t wtb[64 * K1PAD];   // 20480 B, W1 transposed [n][k] bf16
    __shared__ float    dsv[64];
    int t = threadIdx.x;
    int n0 = blockIdx.x * 64;
    {
        // stage x tile (fp32 -> bf16)
        const float4* x4 = (const float4*)x;
        for (int i = t; i < 64 * K1_4; i += 256) {
            int r = i / K1_4, c = i % K1_4;
            int n = n0 + r; if (n >= N_NODES) n = N_NODES - 1;
            float4 v = x4[(long long)n * K1_4 + c];
            *(uint2*)&xsb[r * K1PAD + 4 * c] =
                make_uint2(pack2(v.x, v.y), pack2(v.z, v.w));
        }
        // zero-pad x K range [136,160): 12 u32 per row
        for (int i = t; i < 64 * 12; i += 256) {
            int r = i / 12, c = i % 12;
            *(unsigned*)&xsb[r * K1PAD + N_FEAT + 2 * c] = 0;
        }
        // stage W1 transposed: wtb[n][k] = bf16(W1[k*64+n])
        for (int i = t; i < N_FEAT * HIDDEN; i += 256) {
            int n = i & 63, k = i >> 6;
            wtb[n * K1PAD + k] = f2b(W1[i]);
        }
        for (int i = t; i < 64 * 12; i += 256) {
            int n = i / 12, c = i % 12;
            *(unsigned*)&wtb[n * K1PAD + N_FEAT + 2 * c] = 0;
        }
        if (t < 64) {
            int n = n0 + t; if (n >= N_NODES) n = N_NODES - 1;
            dsv[t] = dinv[n];
        }
    }
    __syncthreads();
    int w = t >> 6, lane = t & 63;
    int quad = lane >> 4, l16 = lane & 15;
    f32x4 acc[4] = {{0,0,0,0},{0,0,0,0},{0,0,0,0},{0,0,0,0}};
#pragma unroll
    for (int kc = 0; kc < K1PAD / 32; ++kc) {
        bf16x8 a = *(const bf16x8*)&xsb[(w * 16 + l16) * K1PAD + kc * 32 + quad * 8];
#pragma unroll
        for (int nt = 0; nt < 4; ++nt) {
            bf16x8 b = *(const bf16x8*)&wtb[(nt * 16 + l16) * K1PAD + kc * 32 + quad * 8];
            acc[nt] = __builtin_amdgcn_mfma_f32_16x16x32_bf16(a, b, acc[nt], 0, 0, 0);
        }
    }
#pragma unroll
    for (int r = 0; r < 4; ++r) {
        int nl = w * 16 + quad * 4 + r;
        int node = n0 + nl;
        if (node < N_NODES) {
            float di = dsv[nl];
#pragma unroll
            for (int nt = 0; nt < 4; ++nt)
                tpb[node * 64 + nt * 16 + l16] = f2b(acc[nt][r] * di);
        }
    }
}

// ========== MFMA mm2: t' = (h @ W2) * dinv -> bf16  (64 -> 64) ==============
__global__ __launch_bounds__(256) void mm2_kernel(const float* __restrict__ h,
                                                  const float* __restrict__ W2,
                                                  const float* __restrict__ dinv,
                                                  ushort_t* __restrict__ tpb) {
    __shared__ ushort_t hsb[64 * K2PAD];   // 9216 B
    __shared__ ushort_t wtb[64 * K2PAD];   // 9216 B, W2 transposed [n][k]
    __shared__ float    dsv[64];
    int t = threadIdx.x;
    int n0 = blockIdx.x * 64;
    {
        const float4* h4 = (const float4*)h;
        for (int i = t; i < 64 * K2_4; i += 256) {
            int r = i / K2_4, c = i % K2_4;
            int n = n0 + r; if (n >= N_NODES) n = N_NODES - 1;
            float4 v = h4[(long long)n * K2_4 + c];
            *(uint2*)&hsb[r * K2PAD + 4 * c] =
                make_uint2(pack2(v.x, v.y), pack2(v.z, v.w));
        }
        for (int i = t; i < 64 * 4; i += 256) {       // pad [64,72)
            int r = i / 4, c = i % 4;
            *(unsigned*)&hsb[r * K2PAD + HIDDEN + 2 * c] = 0;
        }
        for (int i = t; i < HIDDEN * HIDDEN; i += 256) {
            int n = i & 63, k = i >> 6;
            wtb[n * K2PAD + k] = f2b(W2[i]);
        }
        for (int i = t; i < 64 * 4; i += 256) {
            int n = i / 4, c = i % 4;
            *(unsigned*)&wtb[n * K2PAD + HIDDEN + 2 * c] = 0;
        }
        if (t < 64) {
            int n = n0 + t; if (n >= N_NODES) n = N_NODES - 1;
            dsv[t] = dinv[n];
        }
    }
    __syncthreads();
    int w = t >> 6, lane = t & 63;
    int quad = lane >> 4, l16 = lane & 15;
    f32x4 acc[4] = {{0,0,0,0},{0,0,0,0},{0,0,0,0},{0,0,0,0}};
#pragma unroll
    for (int kc = 0; kc < 2; ++kc) {
        bf16x8 a = *(const bf16x8*)&hsb[(w * 16 + l16) * K2PAD + kc * 32 + quad * 8];
#pragma unroll
        for (int nt = 0; nt < 4; ++nt) {
            bf16x8 b = *(const bf16x8*)&wtb[(nt * 16 + l16) * K2PAD + kc * 32 + quad * 8];
            acc[nt] = __builtin_amdgcn_mfma_f32_16x16x32_bf16(a, b, acc[nt], 0, 0, 0);
        }
    }
#pragma unroll
    for (int r = 0; r < 4; ++r) {
        int nl = w * 16 + quad * 4 + r;
        int node = n0 + nl;
        if (node < N_NODES) {
            float di = dsv[nl];
#pragma unroll
            for (int nt = 0; nt < 4; ++nt)
                tpb[node * 64 + nt * 16 + l16] = f2b(acc[nt][r] * di);
        }
    }
}

// ======== edge-parallel segmented reduce over CSR (dst-sorted) ==============
__global__ __launch_bounds__(256, 4) void edge_seg_kernel(const int* __restrict__ csr_src,
                                                          const int* __restrict__ dst_sorted,
                                                          const ushort_t* __restrict__ tpb,
                                                          float* __restrict__ agg) {
    int lane = threadIdx.x & 63;
    int wid  = (blockIdx.x * 256 + threadIdx.x) >> 6;
    const int nw = SEG_BLOCKS * 4;               // 8192 waves
    int i16 = lane & 15;

    int sv = csr_src[wid * CHUNK + i16];
    int dv = dst_sorted[wid * CHUNK + i16];
    for (int c = wid; c < NCHUNK; c += nw) {
        int cn = c + nw;
        int sv_next = sv, dv_next = dv;
        if (cn < NCHUNK) {                        // prefetch next chunk's indices
            sv_next = csr_src[cn * CHUNK + i16];
            dv_next = dst_sorted[cn * CHUNK + i16];
        }

        float vv[CHUNK];
        int dd[CHUNK];
#pragma unroll
        for (int j = 0; j < CHUNK; ++j) {
            int s = __builtin_amdgcn_readlane(sv, j);          // scalar src
            dd[j] = __builtin_amdgcn_readlane(dv, j);          // scalar dst
            vv[j] = b2f(tpb[s * 64 + lane]);                   // independent gather
        }
        float acc = vv[0];
        int dprev = dd[0];
#pragma unroll
        for (int j = 1; j < CHUNK; ++j) {
            if (dd[j] != dprev) {                // wave-uniform branch
                atomicAdd(&agg[dprev * 64 + lane], acc);
                acc = 0.0f;
                dprev = dd[j];
            }
            acc += vv[j];
        }
        atomicAdd(&agg[dprev * 64 + lane], acc);
        sv = sv_next; dv = dv_next;
    }
}

// ---- epilogue 1: h = relu((agg + self) * dinv + b) -------------------------
__global__ __launch_bounds__(256) void epi1_kernel(const float* __restrict__ agg,
                                                   const ushort_t* __restrict__ tpb,
                                                   const float* __restrict__ dinv,
                                                   const float* __restrict__ bias,
                                                   float* __restrict__ h) {
    int idx = blockIdx.x * 256 + threadIdx.x;    // 25000 blocks exact
    int n = idx >> 6, f = idx & 63;
    float v = fmaf(agg[idx] + b2f(tpb[idx]), dinv[n], bias[f]);
    h[idx] = fmaxf(v, 0.0f);
}

// ---- layer-2 epilogue + pool: one BLOCK per graph (4 waves), no atomics ----
__global__ __launch_bounds__(256) void gpool_kernel(const float* __restrict__ agg,
                                                    const ushort_t* __restrict__ tpb,
                                                    const float* __restrict__ dinv,
                                                    const float* __restrict__ bias,
                                                    const int* __restrict__ gstart,
                                                    float* __restrict__ sums,
                                                    float* __restrict__ gcount) {
    __shared__ float red[4][64];
    int lane = threadIdx.x & 63;
    int w = threadIdx.x >> 6;
    int g = blockIdx.x;                      // 512 blocks
    int s = gstart[g], e = gstart[g + 1];
    float b = bias[lane];
    float acc = 0.0f;
    for (int n = s + w; n < e; n += 4) {
        int idx = n * 64 + lane;
        acc += fmaxf(fmaf(agg[idx] + b2f(tpb[idx]), dinv[n], b), 0.0f);
    }
    red[w][lane] = acc;
    __syncthreads();
    if (threadIdx.x < 64) {
        float tot = red[0][lane] + red[1][lane] + red[2][lane] + red[3][lane];
        sums[g * 64 + lane] = tot;
        if (lane == 0) gcount[g] = (float)(e - s);
    }
}

// ---- head: out = (sums/counts) @ Wout + bout -------------------------------
__global__ __launch_bounds__(256) void out_kernel(const float* __restrict__ sums,
                                                  const float* __restrict__ gcount,
                                                  const float* __restrict__ Wout,
                                                  const float* __restrict__ bout,
                                                  float* __restrict__ out) {
    int idx = blockIdx.x * 256 + threadIdx.x;
    if (idx >= NUM_GRAPHS * N_CLASSES) return;
    int g = idx / N_CLASSES, c = idx % N_CLASSES;
    float inv_cnt = 1.0f / fmaxf(gcount[g], 1.0f);
    float acc = 0.0f;
#pragma unroll
    for (int k = 0; k < HIDDEN; ++k)
        acc += sums[g * HIDDEN + k] * Wout[k * N_CLASSES + c];
    out[idx] = acc * inv_cnt + bout[c];
}

extern "C" void kernel_launch(void* const* d_in, const int* in_sizes, int n_in,
                              void* d_out, int out_size, void* d_ws, size_t ws_size,
                              hipStream_t stream) {
    const float* x     = (const float*)d_in[0];
    const int*   ei    = (const int*)d_in[1];
    const int*   batch = (const int*)d_in[2];
    const float* W1    = (const float*)d_in[3];
    const float* b1    = (const float*)d_in[4];
    const float* W2    = (const float*)d_in[5];
    const float* b2    = (const float*)d_in[6];
    const float* Wout  = (const float*)d_in[7];
    const float* bout  = (const float*)d_in[8];
    float* out = (float*)d_out;

    const int* src = ei;
    const int* dst = ei + N_EDGES;

    // -------- workspace layout (~73.5 MB) --------
    char* p = (char*)d_ws;
    int*      row_ptr   = (int*)p;      p += (NP_PAD + 256) * sizeof(int);
    int*      cnt       = (int*)p;      p += NP_PAD * sizeof(int);   // hist, then cursor
    int*      partials  = (int*)p;      p += 256 * sizeof(int);
    int*      gstart    = (int*)p;      p += (NUM_GRAPHS + 64) * sizeof(int);
    int*      csr_src   = (int*)p;      p += (size_t)N_EDGES * sizeof(int);   // 4 MB
    int*      dst_sorted= (int*)p;      p += (size_t)N_EDGES * sizeof(int);   // 4 MB
    float*    dinv      = (float*)p;    p += NP_PAD * sizeof(float);
    ushort_t* tpb       = (ushort_t*)p; p += (size_t)N_NODES * HIDDEN * sizeof(ushort_t);
    float*    hbuf      = (float*)p;    p += (size_t)N_NODES * HIDDEN * sizeof(float);
    float*    agg       = (float*)p;    p += (size_t)N_NODES * HIDDEN * sizeof(float);
    float*    sums      = (float*)p;    p += NUM_GRAPHS * HIDDEN * sizeof(float);
    float*    gcount    = (float*)p;    p += NUM_GRAPHS * sizeof(float);

    const int NB_E  = (N_EDGES + 255) / 256;
    const int NB_N  = (N_NODES + 255) / 256;
    const int NB_MM = (N_NODES + 63) / 64;    // 1563 (last block guarded)
    const int NB_EP = N_NODES * HIDDEN / 256; // 25000 exact

    // -------- CSR build + graph bounds --------
    hipMemsetAsync(cnt, 0, NP_PAD * sizeof(int), stream);
    hist_kernel<<<NB_E, 256, 0, stream>>>(dst, cnt);
    scan1_kernel<<<SCAN_BLKS, 256, 0, stream>>>(cnt, row_ptr, partials);
    scan2_kernel<<<1, 128, 0, stream>>>(partials);
    scan3_kernel<<<NP_PAD / 256, 256, 0, stream>>>(row_ptr, cnt, partials);
    scatter_kernel<<<XCD * NB_E, 256, 0, stream>>>(src, dst, cnt, csr_src);
    expand_kernel<<<NB_N, 256, 0, stream>>>(row_ptr, dst_sorted);
    dinv_kernel<<<NB_N, 256, 0, stream>>>(row_ptr, dinv);
    gbounds_kernel<<<3, 256, 0, stream>>>(batch, gstart);

    hipMemsetAsync(agg, 0, (size_t)N_NODES * HIDDEN * sizeof(float), stream);

    // -------- layer 1 --------
    mm1_kernel<<<NB_MM, 256, 0, stream>>>(x, W1, dinv, tpb);
    edge_seg_kernel<<<SEG_BLOCKS, 256, 0, stream>>>(csr_src, dst_sorted, tpb, agg);
    epi1_kernel<<<NB_EP, 256, 0, stream>>>(agg, tpb, dinv, b1, hbuf);

    // -------- layer 2 (epilogue + pool fused, no atomics) --------
    mm2_kernel<<<NB_MM, 256, 0, stream>>>(hbuf, W2, dinv, tpb);
    hipMemsetAsync(agg, 0, (size_t)N_NODES * HIDDEN * sizeof(float), stream);
    edge_seg_kernel<<<SEG_BLOCKS, 256, 0, stream>>>(csr_src, dst_sorted, tpb, agg);
    gpool_kernel<<<NUM_GRAPHS, 256, 0, stream>>>(agg, tpb, dinv, b2, gstart,
                                                 sums, gcount);

    // -------- head --------
    out_kernel<<<(NUM_GRAPHS * N_CLASSES + 255) / 256, 256, 0, stream>>>(
        sums, gcount, Wout, bout, out);
}

// Round 13
// 353.481 us; speedup vs baseline: 1.1287x; 1.0091x over previous
//
#include <hip/hip_runtime.h>
#include <hip/hip_bf16.h>

#define N_NODES   100000
#define N_EDGES   1000000
#define N_FEAT    136
#define HIDDEN    64
#define N_CLASSES 2
#define NUM_GRAPHS 512

#define NP_PAD    100352          // 98 * 1024
#define SCAN_BLKS 98

#define CHUNK      16
#define NCHUNK     (N_EDGES / CHUNK)   // 62500 exact
#define SEG_BLOCKS 2048                // 8192 waves = 32/CU capacity

#define XCD        8
#define PART_N     (N_NODES / XCD)     // 12500 exact

#define K1_4 (N_FEAT / 4)              // 34
#define K2_4 (HIDDEN / 4)              // 16

#define K1PAD 160                      // 136 padded to 5*32, row stride (u16)
#define K2PAD 72                       // 64 + 8 pad to break bank alias

typedef unsigned short ushort_t;
typedef __attribute__((ext_vector_type(8))) short bf16x8;   // MFMA A/B frag
typedef __attribute__((ext_vector_type(4))) float f32x4;    // MFMA C/D frag

// fp32 -> bf16 (RTNE), bf16 -> fp32
__device__ __forceinline__ ushort_t f2b(float v) {
    unsigned b = __float_as_uint(v);
    return (ushort_t)((b + 0x7FFF + ((b >> 16) & 1)) >> 16);
}
__device__ __forceinline__ float b2f(ushort_t u) {
    return __uint_as_float(((unsigned)u) << 16);
}
__device__ __forceinline__ unsigned pack2(float a, float b) {
    return (unsigned)f2b(a) | ((unsigned)f2b(b) << 16);
}

// ============================ CSR build =====================================
__global__ __launch_bounds__(256) void hist_kernel(const int* __restrict__ dst,
                                                   int* __restrict__ cnt) {
    int e = blockIdx.x * 256 + threadIdx.x;
    if (e < N_EDGES) {
        int d = __builtin_nontemporal_load(&dst[e]);
        atomicAdd(&cnt[d], 1);
    }
}

__global__ __launch_bounds__(256) void scan1_kernel(const int* __restrict__ cnt,
                                                    int* __restrict__ row_ptr,
                                                    int* __restrict__ partials) {
    __shared__ int sd[256];
    int b = blockIdx.x, t = threadIdx.x;
    int i0 = b * 1024 + t * 4;
    int c0 = (i0 + 0 < N_NODES) ? cnt[i0 + 0] : 0;
    int c1 = (i0 + 1 < N_NODES) ? cnt[i0 + 1] : 0;
    int c2 = (i0 + 2 < N_NODES) ? cnt[i0 + 2] : 0;
    int c3 = (i0 + 3 < N_NODES) ? cnt[i0 + 3] : 0;
    int tsum = c0 + c1 + c2 + c3;
    sd[t] = tsum;
    __syncthreads();
    for (int off = 1; off < 256; off <<= 1) {
        int v = (t >= off) ? sd[t - off] : 0;
        __syncthreads();
        sd[t] += v;
        __syncthreads();
    }
    int excl = sd[t] - tsum;
    row_ptr[i0 + 0] = excl;
    row_ptr[i0 + 1] = excl + c0;
    row_ptr[i0 + 2] = excl + c0 + c1;
    row_ptr[i0 + 3] = excl + c0 + c1 + c2;
    if (t == 255) partials[b] = sd[255];
}

__global__ __launch_bounds__(128) void scan2_kernel(int* __restrict__ partials) {
    __shared__ int sd[128];
    int t = threadIdx.x;
    int v = (t < SCAN_BLKS) ? partials[t] : 0;
    sd[t] = v;
    __syncthreads();
    for (int off = 1; off < 128; off <<= 1) {
        int u = (t >= off) ? sd[t - off] : 0;
        __syncthreads();
        sd[t] += u;
        __syncthreads();
    }
    partials[t] = sd[t] - v;
}

// scan3 + fused expansion: finalize row_ptr, init cursor, and write
// dst_sorted[v .. v+deg) = i (deg read from cnt BEFORE cursor overwrites it)
__global__ __launch_bounds__(256) void scan3_kernel(int* __restrict__ row_ptr,
                                                    const int* __restrict__ cnt,
                                                    int* __restrict__ cursor,
                                                    const int* __restrict__ partials,
                                                    int* __restrict__ dst_sorted) {
    int i = blockIdx.x * 256 + threadIdx.x;
    if (i < N_NODES) {
        int v = row_ptr[i] + partials[i >> 10];
        int deg = cnt[i];
        row_ptr[i] = v;
        cursor[i]  = v;
        for (int j = v; j < v + deg; ++j) dst_sorted[j] = i;
    }
    if (i == N_NODES) row_ptr[N_NODES] = N_EDGES;
}

// XCD-partitioned scatter: partition p (= blockIdx&7) handles dst range
// [p*12500,(p+1)*12500). Streaming reads are non-temporal so dirty csr_src
// lines stay resident in the XCD's L2 until full.
__global__ __launch_bounds__(256) void scatter_kernel(const int* __restrict__ src,
                                                      const int* __restrict__ dst,
                                                      int* __restrict__ cursor,
                                                      int* __restrict__ csr_src) {
    int part = blockIdx.x & (XCD - 1);
    int e = (blockIdx.x >> 3) * 256 + threadIdx.x;
    if (e >= N_EDGES) return;
    int d = __builtin_nontemporal_load(&dst[e]);
    int lo = part * PART_N;
    if (d >= lo && d < lo + PART_N) {
        int s = __builtin_nontemporal_load(&src[e]);
        int pos = atomicAdd(&cursor[d], 1);
        csr_src[pos] = s;
    }
}

__global__ __launch_bounds__(256) void dinv_kernel(const int* __restrict__ row_ptr,
                                                   float* __restrict__ dinv) {
    int i = blockIdx.x * 256 + threadIdx.x;
    if (i < N_NODES)
        dinv[i] = rsqrtf((float)(row_ptr[i + 1] - row_ptr[i] + 1));  // +1 self-loop
}

// ---- graph boundaries: gstart[g] = lower_bound(batch, g) -------------------
__global__ __launch_bounds__(256) void gbounds_kernel(const int* __restrict__ batch,
                                                      int* __restrict__ gstart) {
    int g = blockIdx.x * 256 + threadIdx.x;
    if (g > NUM_GRAPHS) return;
    int lo = 0, hi = N_NODES;
    while (lo < hi) {
        int mid = (lo + hi) >> 1;
        if (batch[mid] < g) lo = mid + 1; else hi = mid;
    }
    gstart[g] = lo;
}

// ========== MFMA mm1: t' = (x @ W1) * dinv -> bf16  (136 -> 64) =============
__global__ __launch_bounds__(256) void mm1_kernel(const float* __restrict__ x,
                                                  const float* __restrict__ W1,
                                                  const float* __restrict__ dinv,
                                                  ushort_t* __restrict__ tpb) {
    __shared__ ushort_t xsb[64 * K1PAD];   // 20480 B, node-major bf16
    __shared__ ushort_t wtb[64 * K1PAD];   // 20480 B, W1 transposed [n][k] bf16
    __shared__ float    dsv[64];
    int t = threadIdx.x;
    int n0 = blockIdx.x * 64;
    {
        const float4* x4 = (const float4*)x;
        for (int i = t; i < 64 * K1_4; i += 256) {
            int r = i / K1_4, c = i % K1_4;
            int n = n0 + r; if (n >= N_NODES) n = N_NODES - 1;
            float4 v = x4[(long long)n * K1_4 + c];
            *(uint2*)&xsb[r * K1PAD + 4 * c] =
                make_uint2(pack2(v.x, v.y), pack2(v.z, v.w));
        }
        for (int i = t; i < 64 * 12; i += 256) {
            int r = i / 12, c = i % 12;
            *(unsigned*)&xsb[r * K1PAD + N_FEAT + 2 * c] = 0;
        }
        for (int i = t; i < N_FEAT * HIDDEN; i += 256) {
            int n = i & 63, k = i >> 6;
            wtb[n * K1PAD + k] = f2b(W1[i]);
        }
        for (int i = t; i < 64 * 12; i += 256) {
            int n = i / 12, c = i % 12;
            *(unsigned*)&wtb[n * K1PAD + N_FEAT + 2 * c] = 0;
        }
        if (t < 64) {
            int n = n0 + t; if (n >= N_NODES) n = N_NODES - 1;
            dsv[t] = dinv[n];
        }
    }
    __syncthreads();
    int w = t >> 6, lane = t & 63;
    int quad = lane >> 4, l16 = lane & 15;
    f32x4 acc[4] = {{0,0,0,0},{0,0,0,0},{0,0,0,0},{0,0,0,0}};
#pragma unroll
    for (int kc = 0; kc < K1PAD / 32; ++kc) {
        bf16x8 a = *(const bf16x8*)&xsb[(w * 16 + l16) * K1PAD + kc * 32 + quad * 8];
#pragma unroll
        for (int nt = 0; nt < 4; ++nt) {
            bf16x8 b = *(const bf16x8*)&wtb[(nt * 16 + l16) * K1PAD + kc * 32 + quad * 8];
            acc[nt] = __builtin_amdgcn_mfma_f32_16x16x32_bf16(a, b, acc[nt], 0, 0, 0);
        }
    }
#pragma unroll
    for (int r = 0; r < 4; ++r) {
        int nl = w * 16 + quad * 4 + r;
        int node = n0 + nl;
        if (node < N_NODES) {
            float di = dsv[nl];
#pragma unroll
            for (int nt = 0; nt < 4; ++nt)
                tpb[node * 64 + nt * 16 + l16] = f2b(acc[nt][r] * di);
        }
    }
}

// ========== MFMA mm2: t' = (h @ W2) * dinv -> bf16  (64 -> 64) ==============
__global__ __launch_bounds__(256) void mm2_kernel(const float* __restrict__ h,
                                                  const float* __restrict__ W2,
                                                  const float* __restrict__ dinv,
                                                  ushort_t* __restrict__ tpb) {
    __shared__ ushort_t hsb[64 * K2PAD];   // 9216 B
    __shared__ ushort_t wtb[64 * K2PAD];   // 9216 B, W2 transposed [n][k]
    __shared__ float    dsv[64];
    int t = threadIdx.x;
    int n0 = blockIdx.x * 64;
    {
        const float4* h4 = (const float4*)h;
        for (int i = t; i < 64 * K2_4; i += 256) {
            int r = i / K2_4, c = i % K2_4;
            int n = n0 + r; if (n >= N_NODES) n = N_NODES - 1;
            float4 v = h4[(long long)n * K2_4 + c];
            *(uint2*)&hsb[r * K2PAD + 4 * c] =
                make_uint2(pack2(v.x, v.y), pack2(v.z, v.w));
        }
        for (int i = t; i < 64 * 4; i += 256) {       // pad [64,72)
            int r = i / 4, c = i % 4;
            *(unsigned*)&hsb[r * K2PAD + HIDDEN + 2 * c] = 0;
        }
        for (int i = t; i < HIDDEN * HIDDEN; i += 256) {
            int n = i & 63, k = i >> 6;
            wtb[n * K2PAD + k] = f2b(W2[i]);
        }
        for (int i = t; i < 64 * 4; i += 256) {
            int n = i / 4, c = i % 4;
            *(unsigned*)&wtb[n * K2PAD + HIDDEN + 2 * c] = 0;
        }
        if (t < 64) {
            int n = n0 + t; if (n >= N_NODES) n = N_NODES - 1;
            dsv[t] = dinv[n];
        }
    }
    __syncthreads();
    int w = t >> 6, lane = t & 63;
    int quad = lane >> 4, l16 = lane & 15;
    f32x4 acc[4] = {{0,0,0,0},{0,0,0,0},{0,0,0,0},{0,0,0,0}};
#pragma unroll
    for (int kc = 0; kc < 2; ++kc) {
        bf16x8 a = *(const bf16x8*)&hsb[(w * 16 + l16) * K2PAD + kc * 32 + quad * 8];
#pragma unroll
        for (int nt = 0; nt < 4; ++nt) {
            bf16x8 b = *(const bf16x8*)&wtb[(nt * 16 + l16) * K2PAD + kc * 32 + quad * 8];
            acc[nt] = __builtin_amdgcn_mfma_f32_16x16x32_bf16(a, b, acc[nt], 0, 0, 0);
        }
    }
#pragma unroll
    for (int r = 0; r < 4; ++r) {
        int nl = w * 16 + quad * 4 + r;
        int node = n0 + nl;
        if (node < N_NODES) {
            float di = dsv[nl];
#pragma unroll
            for (int nt = 0; nt < 4; ++nt)
                tpb[node * 64 + nt * 16 + l16] = f2b(acc[nt][r] * di);
        }
    }
}

// ======== edge-parallel segmented reduce over CSR (dst-sorted) ==============
__global__ __launch_bounds__(256, 4) void edge_seg_kernel(const int* __restrict__ csr_src,
                                                          const int* __restrict__ dst_sorted,
                                                          const ushort_t* __restrict__ tpb,
                                                          float* __restrict__ agg) {
    int lane = threadIdx.x & 63;
    int wid  = (blockIdx.x * 256 + threadIdx.x) >> 6;
    const int nw = SEG_BLOCKS * 4;               // 8192 waves
    int i16 = lane & 15;

    int sv = csr_src[wid * CHUNK + i16];
    int dv = dst_sorted[wid * CHUNK + i16];
    for (int c = wid; c < NCHUNK; c += nw) {
        int cn = c + nw;
        int sv_next = sv, dv_next = dv;
        if (cn < NCHUNK) {                        // prefetch next chunk's indices
            sv_next = csr_src[cn * CHUNK + i16];
            dv_next = dst_sorted[cn * CHUNK + i16];
        }

        float vv[CHUNK];
        int dd[CHUNK];
#pragma unroll
        for (int j = 0; j < CHUNK; ++j) {
            int s = __builtin_amdgcn_readlane(sv, j);          // scalar src
            dd[j] = __builtin_amdgcn_readlane(dv, j);          // scalar dst
            vv[j] = b2f(tpb[s * 64 + lane]);                   // independent gather
        }
        float acc = vv[0];
        int dprev = dd[0];
#pragma unroll
        for (int j = 1; j < CHUNK; ++j) {
            if (dd[j] != dprev) {                // wave-uniform branch
                atomicAdd(&agg[dprev * 64 + lane], acc);
                acc = 0.0f;
                dprev = dd[j];
            }
            acc += vv[j];
        }
        atomicAdd(&agg[dprev * 64 + lane], acc);
        sv = sv_next; dv = dv_next;
    }
}

// ---- epilogue 1: h = relu((agg + self) * dinv + b) -------------------------
__global__ __launch_bounds__(256) void epi1_kernel(const float* __restrict__ agg,
                                                   const ushort_t* __restrict__ tpb,
                                                   const float* __restrict__ dinv,
                                                   const float* __restrict__ bias,
                                                   float* __restrict__ h) {
    int idx = blockIdx.x * 256 + threadIdx.x;    // 25000 blocks exact
    int n = idx >> 6, f = idx & 63;
    float v = fmaf(agg[idx] + b2f(tpb[idx]), dinv[n], bias[f]);
    h[idx] = fmaxf(v, 0.0f);
}

// ---- layer-2 epilogue + pool: one BLOCK per graph (4 waves), no atomics ----
__global__ __launch_bounds__(256) void gpool_kernel(const float* __restrict__ agg,
                                                    const ushort_t* __restrict__ tpb,
                                                    const float* __restrict__ dinv,
                                                    const float* __restrict__ bias,
                                                    const int* __restrict__ gstart,
                                                    float* __restrict__ sums,
                                                    float* __restrict__ gcount) {
    __shared__ float red[4][64];
    int lane = threadIdx.x & 63;
    int w = threadIdx.x >> 6;
    int g = blockIdx.x;                      // 512 blocks
    int s = gstart[g], e = gstart[g + 1];
    float b = bias[lane];
    float acc = 0.0f;
    for (int n = s + w; n < e; n += 4) {
        int idx = n * 64 + lane;
        acc += fmaxf(fmaf(agg[idx] + b2f(tpb[idx]), dinv[n], b), 0.0f);
    }
    red[w][lane] = acc;
    __syncthreads();
    if (threadIdx.x < 64) {
        float tot = red[0][lane] + red[1][lane] + red[2][lane] + red[3][lane];
        sums[g * 64 + lane] = tot;
        if (lane == 0) gcount[g] = (float)(e - s);
    }
}

// ---- head: out = (sums/counts) @ Wout + bout -------------------------------
__global__ __launch_bounds__(256) void out_kernel(const float* __restrict__ sums,
                                                  const float* __restrict__ gcount,
                                                  const float* __restrict__ Wout,
                                                  const float* __restrict__ bout,
                                                  float* __restrict__ out) {
    int idx = blockIdx.x * 256 + threadIdx.x;
    if (idx >= NUM_GRAPHS * N_CLASSES) return;
    int g = idx / N_CLASSES, c = idx % N_CLASSES;
    float inv_cnt = 1.0f / fmaxf(gcount[g], 1.0f);
    float acc = 0.0f;
#pragma unroll
    for (int k = 0; k < HIDDEN; ++k)
        acc += sums[g * HIDDEN + k] * Wout[k * N_CLASSES + c];
    out[idx] = acc * inv_cnt + bout[c];
}

extern "C" void kernel_launch(void* const* d_in, const int* in_sizes, int n_in,
                              void* d_out, int out_size, void* d_ws, size_t ws_size,
                              hipStream_t stream) {
    const float* x     = (const float*)d_in[0];
    const int*   ei    = (const int*)d_in[1];
    const int*   batch = (const int*)d_in[2];
    const float* W1    = (const float*)d_in[3];
    const float* b1    = (const float*)d_in[4];
    const float* W2    = (const float*)d_in[5];
    const float* b2    = (const float*)d_in[6];
    const float* Wout  = (const float*)d_in[7];
    const float* bout  = (const float*)d_in[8];
    float* out = (float*)d_out;

    const int* src = ei;
    const int* dst = ei + N_EDGES;

    // -------- workspace layout (~74 MB) --------
    char* p = (char*)d_ws;
    int*      row_ptr   = (int*)p;      p += (NP_PAD + 256) * sizeof(int);
    int*      cnt       = (int*)p;      p += NP_PAD * sizeof(int);   // histogram
    int*      cursor    = (int*)p;      p += NP_PAD * sizeof(int);   // scatter cursor
    int*      partials  = (int*)p;      p += 256 * sizeof(int);
    int*      gstart    = (int*)p;      p += (NUM_GRAPHS + 64) * sizeof(int);
    int*      csr_src   = (int*)p;      p += (size_t)N_EDGES * sizeof(int);   // 4 MB
    int*      dst_sorted= (int*)p;      p += (size_t)N_EDGES * sizeof(int);   // 4 MB
    float*    dinv      = (float*)p;    p += NP_PAD * sizeof(float);
    ushort_t* tpb       = (ushort_t*)p; p += (size_t)N_NODES * HIDDEN * sizeof(ushort_t);
    float*    hbuf      = (float*)p;    p += (size_t)N_NODES * HIDDEN * sizeof(float);
    float*    agg       = (float*)p;    p += (size_t)N_NODES * HIDDEN * sizeof(float);
    float*    sums      = (float*)p;    p += NUM_GRAPHS * HIDDEN * sizeof(float);
    float*    gcount    = (float*)p;    p += NUM_GRAPHS * sizeof(float);

    const int NB_E  = (N_EDGES + 255) / 256;
    const int NB_N  = (N_NODES + 255) / 256;
    const int NB_MM = (N_NODES + 63) / 64;    // 1563 (last block guarded)
    const int NB_EP = N_NODES * HIDDEN / 256; // 25000 exact

    // -------- CSR build + graph bounds --------
    hipMemsetAsync(cnt, 0, NP_PAD * sizeof(int), stream);
    hist_kernel<<<NB_E, 256, 0, stream>>>(dst, cnt);
    scan1_kernel<<<SCAN_BLKS, 256, 0, stream>>>(cnt, row_ptr, partials);
    scan2_kernel<<<1, 128, 0, stream>>>(partials);
    scan3_kernel<<<NP_PAD / 256, 256, 0, stream>>>(row_ptr, cnt, cursor, partials,
                                                   dst_sorted);
    scatter_kernel<<<XCD * NB_E, 256, 0, stream>>>(src, dst, cursor, csr_src);
    dinv_kernel<<<NB_N, 256, 0, stream>>>(row_ptr, dinv);
    gbounds_kernel<<<3, 256, 0, stream>>>(batch, gstart);

    hipMemsetAsync(agg, 0, (size_t)N_NODES * HIDDEN * sizeof(float), stream);

    // -------- layer 1 --------
    mm1_kernel<<<NB_MM, 256, 0, stream>>>(x, W1, dinv, tpb);
    edge_seg_kernel<<<SEG_BLOCKS, 256, 0, stream>>>(csr_src, dst_sorted, tpb, agg);
    epi1_kernel<<<NB_EP, 256, 0, stream>>>(agg, tpb, dinv, b1, hbuf);

    // -------- layer 2 (epilogue + pool fused, no atomics) --------
    mm2_kernel<<<NB_MM, 256, 0, stream>>>(hbuf, W2, dinv, tpb);
    hipMemsetAsync(agg, 0, (size_t)N_NODES * HIDDEN * sizeof(float), stream);
    edge_seg_kernel<<<SEG_BLOCKS, 256, 0, stream>>>(csr_src, dst_sorted, tpb, agg);
    gpool_kernel<<<NUM_GRAPHS, 256, 0, stream>>>(agg, tpb, dinv, b2, gstart,
                                                 sums, gcount);

    // -------- head --------
    out_kernel<<<(NUM_GRAPHS * N_CLASSES + 255) / 256, 256, 0, stream>>>(
        sums, gcount, Wout, bout, out);
}

// Round 14
// 340.909 us; speedup vs baseline: 1.1703x; 1.0369x over previous
//
#include <hip/hip_runtime.h>
#include <hip/hip_bf16.h>

#define N_NODES   100000
#define N_EDGES   1000000
#define N_FEAT    136
#define HIDDEN    64
#define N_CLASSES 2
#define NUM_GRAPHS 512

#define NP_PAD    100352          // 98 * 1024
#define SCAN_BLKS 98

#define CHUNK      16
#define NCHUNK     (N_EDGES / CHUNK)   // 62500 exact
#define SEG_BLOCKS 2048                // 8192 waves = 32/CU capacity

#define XCD        8
#define PART_N     (N_NODES / XCD)     // 12500 exact

#define K1_4 (N_FEAT / 4)              // 34
#define K2_4 (HIDDEN / 4)              // 16

#define K1PAD 160                      // 136 padded to 5*32, row stride (u16)
#define K2PAD 72                       // 64 + 8 pad to break bank alias

typedef unsigned short ushort_t;
typedef __attribute__((ext_vector_type(8))) short bf16x8;   // MFMA A/B frag
typedef __attribute__((ext_vector_type(4))) float f32x4;    // MFMA C/D frag

// fp32 -> bf16 (RTNE), bf16 -> fp32
__device__ __forceinline__ ushort_t f2b(float v) {
    unsigned b = __float_as_uint(v);
    return (ushort_t)((b + 0x7FFF + ((b >> 16) & 1)) >> 16);
}
__device__ __forceinline__ float b2f(ushort_t u) {
    return __uint_as_float(((unsigned)u) << 16);
}
__device__ __forceinline__ unsigned pack2(float a, float b) {
    return (unsigned)f2b(a) | ((unsigned)f2b(b) << 16);
}

// ============================ CSR build =====================================
__global__ __launch_bounds__(256) void hist_kernel(const int* __restrict__ dst,
                                                   int* __restrict__ cnt) {
    int e = blockIdx.x * 256 + threadIdx.x;
    if (e < N_EDGES) {
        int d = __builtin_nontemporal_load(&dst[e]);
        atomicAdd(&cnt[d], 1);
    }
}

__global__ __launch_bounds__(256) void scan1_kernel(const int* __restrict__ cnt,
                                                    int* __restrict__ row_ptr,
                                                    int* __restrict__ partials) {
    __shared__ int sd[256];
    int b = blockIdx.x, t = threadIdx.x;
    int i0 = b * 1024 + t * 4;
    int c0 = (i0 + 0 < N_NODES) ? cnt[i0 + 0] : 0;
    int c1 = (i0 + 1 < N_NODES) ? cnt[i0 + 1] : 0;
    int c2 = (i0 + 2 < N_NODES) ? cnt[i0 + 2] : 0;
    int c3 = (i0 + 3 < N_NODES) ? cnt[i0 + 3] : 0;
    int tsum = c0 + c1 + c2 + c3;
    sd[t] = tsum;
    __syncthreads();
    for (int off = 1; off < 256; off <<= 1) {
        int v = (t >= off) ? sd[t - off] : 0;
        __syncthreads();
        sd[t] += v;
        __syncthreads();
    }
    int excl = sd[t] - tsum;
    row_ptr[i0 + 0] = excl;
    row_ptr[i0 + 1] = excl + c0;
    row_ptr[i0 + 2] = excl + c0 + c1;
    row_ptr[i0 + 3] = excl + c0 + c1 + c2;
    if (t == 255) partials[b] = sd[255];
}

__global__ __launch_bounds__(128) void scan2_kernel(int* __restrict__ partials) {
    __shared__ int sd[128];
    int t = threadIdx.x;
    int v = (t < SCAN_BLKS) ? partials[t] : 0;
    sd[t] = v;
    __syncthreads();
    for (int off = 1; off < 128; off <<= 1) {
        int u = (t >= off) ? sd[t - off] : 0;
        __syncthreads();
        sd[t] += u;
        __syncthreads();
    }
    partials[t] = sd[t] - v;
}

// scan3 + fused expansion: finalize row_ptr, init cursor, and write
// dst_sorted[v .. v+deg) = i
__global__ __launch_bounds__(256) void scan3_kernel(int* __restrict__ row_ptr,
                                                    const int* __restrict__ cnt,
                                                    int* __restrict__ cursor,
                                                    const int* __restrict__ partials,
                                                    int* __restrict__ dst_sorted) {
    int i = blockIdx.x * 256 + threadIdx.x;
    if (i < N_NODES) {
        int v = row_ptr[i] + partials[i >> 10];
        int deg = cnt[i];
        row_ptr[i] = v;
        cursor[i]  = v;
        for (int j = v; j < v + deg; ++j) dst_sorted[j] = i;
    }
    if (i == N_NODES) row_ptr[N_NODES] = N_EDGES;
}

// XCD-partitioned scatter
__global__ __launch_bounds__(256) void scatter_kernel(const int* __restrict__ src,
                                                      const int* __restrict__ dst,
                                                      int* __restrict__ cursor,
                                                      int* __restrict__ csr_src) {
    int part = blockIdx.x & (XCD - 1);
    int e = (blockIdx.x >> 3) * 256 + threadIdx.x;
    if (e >= N_EDGES) return;
    int d = __builtin_nontemporal_load(&dst[e]);
    int lo = part * PART_N;
    if (d >= lo && d < lo + PART_N) {
        int s = __builtin_nontemporal_load(&src[e]);
        int pos = atomicAdd(&cursor[d], 1);
        csr_src[pos] = s;
    }
}

__global__ __launch_bounds__(256) void dinv_kernel(const int* __restrict__ row_ptr,
                                                   float* __restrict__ dinv) {
    int i = blockIdx.x * 256 + threadIdx.x;
    if (i < N_NODES)
        dinv[i] = rsqrtf((float)(row_ptr[i + 1] - row_ptr[i] + 1));  // +1 self-loop
}

// ---- graph boundaries: gstart[g] = lower_bound(batch, g) -------------------
__global__ __launch_bounds__(256) void gbounds_kernel(const int* __restrict__ batch,
                                                      int* __restrict__ gstart) {
    int g = blockIdx.x * 256 + threadIdx.x;
    if (g > NUM_GRAPHS) return;
    int lo = 0, hi = N_NODES;
    while (lo < hi) {
        int mid = (lo + hi) >> 1;
        if (batch[mid] < g) lo = mid + 1; else hi = mid;
    }
    gstart[g] = lo;
}

// ========== MFMA mm1: t' = (x @ W1) * dinv -> bf16  (136 -> 64) =============
__global__ __launch_bounds__(256) void mm1_kernel(const float* __restrict__ x,
                                                  const float* __restrict__ W1,
                                                  const float* __restrict__ dinv,
                                                  ushort_t* __restrict__ tpb) {
    __shared__ ushort_t xsb[64 * K1PAD];   // 20480 B, node-major bf16
    __shared__ ushort_t wtb[64 * K1PAD];   // 20480 B, W1 transposed [n][k] bf16
    __shared__ float    dsv[64];
    int t = threadIdx.x;
    int n0 = blockIdx.x * 64;
    {
        const float4* x4 = (const float4*)x;
        for (int i = t; i < 64 * K1_4; i += 256) {
            int r = i / K1_4, c = i % K1_4;
            int n = n0 + r; if (n >= N_NODES) n = N_NODES - 1;
            float4 v = x4[(long long)n * K1_4 + c];
            *(uint2*)&xsb[r * K1PAD + 4 * c] =
                make_uint2(pack2(v.x, v.y), pack2(v.z, v.w));
        }
        for (int i = t; i < 64 * 12; i += 256) {
            int r = i / 12, c = i % 12;
            *(unsigned*)&xsb[r * K1PAD + N_FEAT + 2 * c] = 0;
        }
        for (int i = t; i < N_FEAT * HIDDEN; i += 256) {
            int n = i & 63, k = i >> 6;
            wtb[n * K1PAD + k] = f2b(W1[i]);
        }
        for (int i = t; i < 64 * 12; i += 256) {
            int n = i / 12, c = i % 12;
            *(unsigned*)&wtb[n * K1PAD + N_FEAT + 2 * c] = 0;
        }
        if (t < 64) {
            int n = n0 + t; if (n >= N_NODES) n = N_NODES - 1;
            dsv[t] = dinv[n];
        }
    }
    __syncthreads();
    int w = t >> 6, lane = t & 63;
    int quad = lane >> 4, l16 = lane & 15;
    f32x4 acc[4] = {{0,0,0,0},{0,0,0,0},{0,0,0,0},{0,0,0,0}};
#pragma unroll
    for (int kc = 0; kc < K1PAD / 32; ++kc) {
        bf16x8 a = *(const bf16x8*)&xsb[(w * 16 + l16) * K1PAD + kc * 32 + quad * 8];
#pragma unroll
        for (int nt = 0; nt < 4; ++nt) {
            bf16x8 b = *(const bf16x8*)&wtb[(nt * 16 + l16) * K1PAD + kc * 32 + quad * 8];
            acc[nt] = __builtin_amdgcn_mfma_f32_16x16x32_bf16(a, b, acc[nt], 0, 0, 0);
        }
    }
#pragma unroll
    for (int r = 0; r < 4; ++r) {
        int nl = w * 16 + quad * 4 + r;
        int node = n0 + nl;
        if (node < N_NODES) {
            float di = dsv[nl];
#pragma unroll
            for (int nt = 0; nt < 4; ++nt)
                tpb[node * 64 + nt * 16 + l16] = f2b(acc[nt][r] * di);
        }
    }
}

// ========== MFMA mm2 + fused layer-1 epilogue ===============================
// h = relu((agg + tpb)*dinv + b1) computed inline during staging (bf16 LDS);
// each block re-zeros its own agg tile (replaces the 25.6 MB memset);
// then t2' = (h @ W2) * dinv -> tpb (in-place rewrite of this tile's rows).
__global__ __launch_bounds__(256) void mm2_kernel(float* __restrict__ agg,
                                                  ushort_t* __restrict__ tpb,
                                                  const float* __restrict__ W2,
                                                  const float* __restrict__ dinv,
                                                  const float* __restrict__ bias,
                                                  int nb_dummy) {
    __shared__ ushort_t hsb[64 * K2PAD];   // 9216 B
    __shared__ ushort_t wtb[64 * K2PAD];   // 9216 B, W2 transposed [n][k]
    __shared__ float    dsv[64];
    __shared__ float    bsv[64];
    int t = threadIdx.x;
    int n0 = blockIdx.x * 64;
    if (t < 64) {
        int n = n0 + t; if (n >= N_NODES) n = N_NODES - 1;
        dsv[t] = dinv[n];
        bsv[t] = bias[t];
    }
    __syncthreads();
    {
        // W2 transposed
        for (int i = t; i < HIDDEN * HIDDEN; i += 256) {
            int n = i & 63, k = i >> 6;
            wtb[n * K2PAD + k] = f2b(W2[i]);
        }
        for (int i = t; i < 64 * 4; i += 256) {
            int n = i / 4, c = i % 4;
            *(unsigned*)&wtb[n * K2PAD + HIDDEN + 2 * c] = 0;
        }
        // fused epilogue-1: h tile from agg + tpb(self), then zero agg tile
        for (int i = t; i < 64 * 16; i += 256) {
            int r = i >> 4, c = i & 15;            // c = float4 index
            int n_raw = n0 + r;
            int n = (n_raw < N_NODES) ? n_raw : N_NODES - 1;
            float4 va = ((const float4*)agg)[n * 16 + c];
            uint2 ut = *(const uint2*)&tpb[n * 64 + c * 4];
            float di = dsv[r];
            float s0 = b2f((ushort_t)(ut.x & 0xffff));
            float s1 = b2f((ushort_t)(ut.x >> 16));
            float s2 = b2f((ushort_t)(ut.y & 0xffff));
            float s3 = b2f((ushort_t)(ut.y >> 16));
            float h0 = fmaxf(fmaf(va.x + s0, di, bsv[c * 4 + 0]), 0.f);
            float h1 = fmaxf(fmaf(va.y + s1, di, bsv[c * 4 + 1]), 0.f);
            float h2 = fmaxf(fmaf(va.z + s2, di, bsv[c * 4 + 2]), 0.f);
            float h3 = fmaxf(fmaf(va.w + s3, di, bsv[c * 4 + 3]), 0.f);
            *(uint2*)&hsb[r * K2PAD + 4 * c] = make_uint2(pack2(h0, h1), pack2(h2, h3));
            if (n_raw < N_NODES)
                ((float4*)agg)[n * 16 + c] = make_float4(0.f, 0.f, 0.f, 0.f);
        }
        for (int i = t; i < 64 * 4; i += 256) {    // pad [64,72)
            int r = i / 4, c = i % 4;
            *(unsigned*)&hsb[r * K2PAD + HIDDEN + 2 * c] = 0;
        }
    }
    __syncthreads();
    int w = t >> 6, lane = t & 63;
    int quad = lane >> 4, l16 = lane & 15;
    f32x4 acc[4] = {{0,0,0,0},{0,0,0,0},{0,0,0,0},{0,0,0,0}};
#pragma unroll
    for (int kc = 0; kc < 2; ++kc) {
        bf16x8 a = *(const bf16x8*)&hsb[(w * 16 + l16) * K2PAD + kc * 32 + quad * 8];
#pragma unroll
        for (int nt = 0; nt < 4; ++nt) {
            bf16x8 b = *(const bf16x8*)&wtb[(nt * 16 + l16) * K2PAD + kc * 32 + quad * 8];
            acc[nt] = __builtin_amdgcn_mfma_f32_16x16x32_bf16(a, b, acc[nt], 0, 0, 0);
        }
    }
#pragma unroll
    for (int r = 0; r < 4; ++r) {
        int nl = w * 16 + quad * 4 + r;
        int node = n0 + nl;
        if (node < N_NODES) {
            float di = dsv[nl];
#pragma unroll
            for (int nt = 0; nt < 4; ++nt)
                tpb[node * 64 + nt * 16 + l16] = f2b(acc[nt][r] * di);
        }
    }
}

// ======== edge-parallel segmented reduce over CSR (dst-sorted) ==============
__global__ __launch_bounds__(256, 4) void edge_seg_kernel(const int* __restrict__ csr_src,
                                                          const int* __restrict__ dst_sorted,
                                                          const ushort_t* __restrict__ tpb,
                                                          float* __restrict__ agg) {
    int lane = threadIdx.x & 63;
    int wid  = (blockIdx.x * 256 + threadIdx.x) >> 6;
    const int nw = SEG_BLOCKS * 4;               // 8192 waves
    int i16 = lane & 15;

    int sv = csr_src[wid * CHUNK + i16];
    int dv = dst_sorted[wid * CHUNK + i16];
    for (int c = wid; c < NCHUNK; c += nw) {
        int cn = c + nw;
        int sv_next = sv, dv_next = dv;
        if (cn < NCHUNK) {                        // prefetch next chunk's indices
            sv_next = csr_src[cn * CHUNK + i16];
            dv_next = dst_sorted[cn * CHUNK + i16];
        }

        float vv[CHUNK];
        int dd[CHUNK];
#pragma unroll
        for (int j = 0; j < CHUNK; ++j) {
            int s = __builtin_amdgcn_readlane(sv, j);          // scalar src
            dd[j] = __builtin_amdgcn_readlane(dv, j);          // scalar dst
            vv[j] = b2f(tpb[s * 64 + lane]);                   // independent gather
        }
        float acc = vv[0];
        int dprev = dd[0];
#pragma unroll
        for (int j = 1; j < CHUNK; ++j) {
            if (dd[j] != dprev) {                // wave-uniform branch
                atomicAdd(&agg[dprev * 64 + lane], acc);
                acc = 0.0f;
                dprev = dd[j];
            }
            acc += vv[j];
        }
        atomicAdd(&agg[dprev * 64 + lane], acc);
        sv = sv_next; dv = dv_next;
    }
}

// ---- layer-2 epilogue + pool: one BLOCK per graph (4 waves), no atomics ----
__global__ __launch_bounds__(256) void gpool_kernel(const float* __restrict__ agg,
                                                    const ushort_t* __restrict__ tpb,
                                                    const float* __restrict__ dinv,
                                                    const float* __restrict__ bias,
                                                    const int* __restrict__ gstart,
                                                    float* __restrict__ sums,
                                                    float* __restrict__ gcount) {
    __shared__ float red[4][64];
    int lane = threadIdx.x & 63;
    int w = threadIdx.x >> 6;
    int g = blockIdx.x;                      // 512 blocks
    int s = gstart[g], e = gstart[g + 1];
    float b = bias[lane];
    float acc = 0.0f;
    for (int n = s + w; n < e; n += 4) {
        int idx = n * 64 + lane;
        acc += fmaxf(fmaf(agg[idx] + b2f(tpb[idx]), dinv[n], b), 0.0f);
    }
    red[w][lane] = acc;
    __syncthreads();
    if (threadIdx.x < 64) {
        float tot = red[0][lane] + red[1][lane] + red[2][lane] + red[3][lane];
        sums[g * 64 + lane] = tot;
        if (lane == 0) gcount[g] = (float)(e - s);
    }
}

// ---- head: out = (sums/counts) @ Wout + bout -------------------------------
__global__ __launch_bounds__(256) void out_kernel(const float* __restrict__ sums,
                                                  const float* __restrict__ gcount,
                                                  const float* __restrict__ Wout,
                                                  const float* __restrict__ bout,
                                                  float* __restrict__ out) {
    int idx = blockIdx.x * 256 + threadIdx.x;
    if (idx >= NUM_GRAPHS * N_CLASSES) return;
    int g = idx / N_CLASSES, c = idx % N_CLASSES;
    float inv_cnt = 1.0f / fmaxf(gcount[g], 1.0f);
    float acc = 0.0f;
#pragma unroll
    for (int k = 0; k < HIDDEN; ++k)
        acc += sums[g * HIDDEN + k] * Wout[k * N_CLASSES + c];
    out[idx] = acc * inv_cnt + bout[c];
}

extern "C" void kernel_launch(void* const* d_in, const int* in_sizes, int n_in,
                              void* d_out, int out_size, void* d_ws, size_t ws_size,
                              hipStream_t stream) {
    const float* x     = (const float*)d_in[0];
    const int*   ei    = (const int*)d_in[1];
    const int*   batch = (const int*)d_in[2];
    const float* W1    = (const float*)d_in[3];
    const float* b1    = (const float*)d_in[4];
    const float* W2    = (const float*)d_in[5];
    const float* b2    = (const float*)d_in[6];
    const float* Wout  = (const float*)d_in[7];
    const float* bout  = (const float*)d_in[8];
    float* out = (float*)d_out;

    const int* src = ei;
    const int* dst = ei + N_EDGES;

    // -------- workspace layout (~48 MB) --------
    char* p = (char*)d_ws;
    int*      row_ptr   = (int*)p;      p += (NP_PAD + 256) * sizeof(int);
    int*      cnt       = (int*)p;      p += NP_PAD * sizeof(int);   // histogram
    int*      cursor    = (int*)p;      p += NP_PAD * sizeof(int);   // scatter cursor
    int*      partials  = (int*)p;      p += 256 * sizeof(int);
    int*      gstart    = (int*)p;      p += (NUM_GRAPHS + 64) * sizeof(int);
    int*      csr_src   = (int*)p;      p += (size_t)N_EDGES * sizeof(int);   // 4 MB
    int*      dst_sorted= (int*)p;      p += (size_t)N_EDGES * sizeof(int);   // 4 MB
    float*    dinv      = (float*)p;    p += NP_PAD * sizeof(float);
    ushort_t* tpb       = (ushort_t*)p; p += (size_t)N_NODES * HIDDEN * sizeof(ushort_t);
    float*    agg       = (float*)p;    p += (size_t)N_NODES * HIDDEN * sizeof(float);
    float*    sums      = (float*)p;    p += NUM_GRAPHS * HIDDEN * sizeof(float);
    float*    gcount    = (float*)p;    p += NUM_GRAPHS * sizeof(float);

    const int NB_E  = (N_EDGES + 255) / 256;
    const int NB_N  = (N_NODES + 255) / 256;
    const int NB_MM = (N_NODES + 63) / 64;    // 1563 (last block guarded)

    // -------- CSR build + graph bounds --------
    hipMemsetAsync(cnt, 0, NP_PAD * sizeof(int), stream);
    hist_kernel<<<NB_E, 256, 0, stream>>>(dst, cnt);
    scan1_kernel<<<SCAN_BLKS, 256, 0, stream>>>(cnt, row_ptr, partials);
    scan2_kernel<<<1, 128, 0, stream>>>(partials);
    scan3_kernel<<<NP_PAD / 256, 256, 0, stream>>>(row_ptr, cnt, cursor, partials,
                                                   dst_sorted);
    scatter_kernel<<<XCD * NB_E, 256, 0, stream>>>(src, dst, cursor, csr_src);
    dinv_kernel<<<NB_N, 256, 0, stream>>>(row_ptr, dinv);
    gbounds_kernel<<<3, 256, 0, stream>>>(batch, gstart);

    hipMemsetAsync(agg, 0, (size_t)N_NODES * HIDDEN * sizeof(float), stream);

    // -------- layer 1 --------
    mm1_kernel<<<NB_MM, 256, 0, stream>>>(x, W1, dinv, tpb);
    edge_seg_kernel<<<SEG_BLOCKS, 256, 0, stream>>>(csr_src, dst_sorted, tpb, agg);

    // -------- layer 2: mm2 fuses epilogue-1 (b1) + agg re-zero --------
    mm2_kernel<<<NB_MM, 256, 0, stream>>>(agg, tpb, W2, dinv, b1, 0);
    edge_seg_kernel<<<SEG_BLOCKS, 256, 0, stream>>>(csr_src, dst_sorted, tpb, agg);
    gpool_kernel<<<NUM_GRAPHS, 256, 0, stream>>>(agg, tpb, dinv, b2, gstart,
                                                 sums, gcount);

    // -------- head --------
    out_kernel<<<(NUM_GRAPHS * N_CLASSES + 255) / 256, 256, 0, stream>>>(
        sums, gcount, Wout, bout, out);
}

// Round 15
// 311.726 us; speedup vs baseline: 1.2799x; 1.0936x over previous
//
#include <hip/hip_runtime.h>
#include <hip/hip_bf16.h>

#define N_NODES   100000
#define N_EDGES   1000000
#define N_FEAT    136
#define HIDDEN    64
#define N_CLASSES 2
#define NUM_GRAPHS 512

#define NP_PAD    100352          // 98 * 1024
#define SCAN_BLKS 98

#define EPW       128                       // edges per wave (contiguous)
#define NWAVE     7813                      // ceil(1e6 / 128)
#define E_PAD     (NWAVE * EPW)             // 1000064
#define SEG_BLOCKS ((NWAVE + 3) / 4)        // 1954 blocks x 4 waves

#define XCD        8
#define PART_N     (N_NODES / XCD)     // 12500 exact

#define K1_4 (N_FEAT / 4)              // 34
#define K2_4 (HIDDEN / 4)              // 16

#define K1PAD 160                      // 136 padded to 5*32, row stride (u16)
#define K2PAD 72                       // 64 + 8 pad to break bank alias

typedef unsigned short ushort_t;
typedef __attribute__((ext_vector_type(8))) short bf16x8;   // MFMA A/B frag
typedef __attribute__((ext_vector_type(4))) float f32x4;    // MFMA C/D frag

// fp32 -> bf16 (RTNE), bf16 -> fp32
__device__ __forceinline__ ushort_t f2b(float v) {
    unsigned b = __float_as_uint(v);
    return (ushort_t)((b + 0x7FFF + ((b >> 16) & 1)) >> 16);
}
__device__ __forceinline__ float b2f(ushort_t u) {
    return __uint_as_float(((unsigned)u) << 16);
}
__device__ __forceinline__ unsigned pack2(float a, float b) {
    return (unsigned)f2b(a) | ((unsigned)f2b(b) << 16);
}

// ============================ CSR build =====================================
__global__ __launch_bounds__(256) void hist_kernel(const int* __restrict__ dst,
                                                   int* __restrict__ cnt) {
    int e = blockIdx.x * 256 + threadIdx.x;
    if (e < N_EDGES) {
        int d = __builtin_nontemporal_load(&dst[e]);
        atomicAdd(&cnt[d], 1);
    }
}

__global__ __launch_bounds__(256) void scan1_kernel(const int* __restrict__ cnt,
                                                    int* __restrict__ row_ptr,
                                                    int* __restrict__ partials) {
    __shared__ int sd[256];
    int b = blockIdx.x, t = threadIdx.x;
    int i0 = b * 1024 + t * 4;
    int c0 = (i0 + 0 < N_NODES) ? cnt[i0 + 0] : 0;
    int c1 = (i0 + 1 < N_NODES) ? cnt[i0 + 1] : 0;
    int c2 = (i0 + 2 < N_NODES) ? cnt[i0 + 2] : 0;
    int c3 = (i0 + 3 < N_NODES) ? cnt[i0 + 3] : 0;
    int tsum = c0 + c1 + c2 + c3;
    sd[t] = tsum;
    __syncthreads();
    for (int off = 1; off < 256; off <<= 1) {
        int v = (t >= off) ? sd[t - off] : 0;
        __syncthreads();
        sd[t] += v;
        __syncthreads();
    }
    int excl = sd[t] - tsum;
    row_ptr[i0 + 0] = excl;
    row_ptr[i0 + 1] = excl + c0;
    row_ptr[i0 + 2] = excl + c0 + c1;
    row_ptr[i0 + 3] = excl + c0 + c1 + c2;
    if (t == 255) partials[b] = sd[255];
}

__global__ __launch_bounds__(128) void scan2_kernel(int* __restrict__ partials) {
    __shared__ int sd[128];
    int t = threadIdx.x;
    int v = (t < SCAN_BLKS) ? partials[t] : 0;
    sd[t] = v;
    __syncthreads();
    for (int off = 1; off < 128; off <<= 1) {
        int u = (t >= off) ? sd[t - off] : 0;
        __syncthreads();
        sd[t] += u;
        __syncthreads();
    }
    partials[t] = sd[t] - v;
}

// scan3: finalize row_ptr, init cursor, fused dst_sorted expansion, fused
// dinv, and sentinel padding of the edge arrays.
__global__ __launch_bounds__(256) void scan3_kernel(int* __restrict__ row_ptr,
                                                    const int* __restrict__ cnt,
                                                    int* __restrict__ cursor,
                                                    const int* __restrict__ partials,
                                                    int* __restrict__ dst_sorted,
                                                    int* __restrict__ csr_src,
                                                    float* __restrict__ dinv) {
    int i = blockIdx.x * 256 + threadIdx.x;
    if (i < N_NODES) {
        int v = row_ptr[i] + partials[i >> 10];
        int deg = cnt[i];
        row_ptr[i] = v;
        cursor[i]  = v;
        dinv[i] = rsqrtf((float)(deg + 1));           // +1 self-loop
        for (int j = v; j < v + deg; ++j) dst_sorted[j] = i;
    }
    if (i == N_NODES) {
        row_ptr[N_NODES] = N_EDGES;
        for (int j = N_EDGES; j < E_PAD; ++j) {       // sentinel pad (64 entries)
            dst_sorted[j] = N_NODES;
            csr_src[j] = 0;
        }
    }
}

// XCD-partitioned scatter
__global__ __launch_bounds__(256) void scatter_kernel(const int* __restrict__ src,
                                                      const int* __restrict__ dst,
                                                      int* __restrict__ cursor,
                                                      int* __restrict__ csr_src) {
    int part = blockIdx.x & (XCD - 1);
    int e = (blockIdx.x >> 3) * 256 + threadIdx.x;
    if (e >= N_EDGES) return;
    int d = __builtin_nontemporal_load(&dst[e]);
    int lo = part * PART_N;
    if (d >= lo && d < lo + PART_N) {
        int s = __builtin_nontemporal_load(&src[e]);
        int pos = atomicAdd(&cursor[d], 1);
        csr_src[pos] = s;
    }
}

// ---- graph boundaries: gstart[g] = lower_bound(batch, g) -------------------
__global__ __launch_bounds__(256) void gbounds_kernel(const int* __restrict__ batch,
                                                      int* __restrict__ gstart) {
    int g = blockIdx.x * 256 + threadIdx.x;
    if (g > NUM_GRAPHS) return;
    int lo = 0, hi = N_NODES;
    while (lo < hi) {
        int mid = (lo + hi) >> 1;
        if (batch[mid] < g) lo = mid + 1; else hi = mid;
    }
    gstart[g] = lo;
}

// ========== MFMA mm1: t' = (x @ W1) * dinv -> bf16  (136 -> 64) =============
__global__ __launch_bounds__(256) void mm1_kernel(const float* __restrict__ x,
                                                  const float* __restrict__ W1,
                                                  const float* __restrict__ dinv,
                                                  ushort_t* __restrict__ tpb) {
    __shared__ ushort_t xsb[64 * K1PAD];   // 20480 B, node-major bf16
    __shared__ ushort_t wtb[64 * K1PAD];   // 20480 B, W1 transposed [n][k] bf16
    __shared__ float    dsv[64];
    int t = threadIdx.x;
    int n0 = blockIdx.x * 64;
    {
        const float4* x4 = (const float4*)x;
        for (int i = t; i < 64 * K1_4; i += 256) {
            int r = i / K1_4, c = i % K1_4;
            int n = n0 + r; if (n >= N_NODES) n = N_NODES - 1;
            float4 v = x4[(long long)n * K1_4 + c];
            *(uint2*)&xsb[r * K1PAD + 4 * c] =
                make_uint2(pack2(v.x, v.y), pack2(v.z, v.w));
        }
        for (int i = t; i < 64 * 12; i += 256) {
            int r = i / 12, c = i % 12;
            *(unsigned*)&xsb[r * K1PAD + N_FEAT + 2 * c] = 0;
        }
        for (int i = t; i < N_FEAT * HIDDEN; i += 256) {
            int n = i & 63, k = i >> 6;
            wtb[n * K1PAD + k] = f2b(W1[i]);
        }
        for (int i = t; i < 64 * 12; i += 256) {
            int n = i / 12, c = i % 12;
            *(unsigned*)&wtb[n * K1PAD + N_FEAT + 2 * c] = 0;
        }
        if (t < 64) {
            int n = n0 + t; if (n >= N_NODES) n = N_NODES - 1;
            dsv[t] = dinv[n];
        }
    }
    __syncthreads();
    int w = t >> 6, lane = t & 63;
    int quad = lane >> 4, l16 = lane & 15;
    f32x4 acc[4] = {{0,0,0,0},{0,0,0,0},{0,0,0,0},{0,0,0,0}};
#pragma unroll
    for (int kc = 0; kc < K1PAD / 32; ++kc) {
        bf16x8 a = *(const bf16x8*)&xsb[(w * 16 + l16) * K1PAD + kc * 32 + quad * 8];
#pragma unroll
        for (int nt = 0; nt < 4; ++nt) {
            bf16x8 b = *(const bf16x8*)&wtb[(nt * 16 + l16) * K1PAD + kc * 32 + quad * 8];
            acc[nt] = __builtin_amdgcn_mfma_f32_16x16x32_bf16(a, b, acc[nt], 0, 0, 0);
        }
    }
#pragma unroll
    for (int r = 0; r < 4; ++r) {
        int nl = w * 16 + quad * 4 + r;
        int node = n0 + nl;
        if (node < N_NODES) {
            float di = dsv[nl];
#pragma unroll
            for (int nt = 0; nt < 4; ++nt)
                tpb[node * 64 + nt * 16 + l16] = f2b(acc[nt][r] * di);
        }
    }
}

// ========== MFMA mm2 + fused layer-1 epilogue ===============================
__global__ __launch_bounds__(256) void mm2_kernel(float* __restrict__ agg,
                                                  ushort_t* __restrict__ tpb,
                                                  const float* __restrict__ W2,
                                                  const float* __restrict__ dinv,
                                                  const float* __restrict__ bias) {
    __shared__ ushort_t hsb[64 * K2PAD];   // 9216 B
    __shared__ ushort_t wtb[64 * K2PAD];   // 9216 B, W2 transposed [n][k]
    __shared__ float    dsv[64];
    __shared__ float    bsv[64];
    int t = threadIdx.x;
    int n0 = blockIdx.x * 64;
    if (t < 64) {
        int n = n0 + t; if (n >= N_NODES) n = N_NODES - 1;
        dsv[t] = dinv[n];
        bsv[t] = bias[t];
    }
    __syncthreads();
    {
        for (int i = t; i < HIDDEN * HIDDEN; i += 256) {
            int n = i & 63, k = i >> 6;
            wtb[n * K2PAD + k] = f2b(W2[i]);
        }
        for (int i = t; i < 64 * 4; i += 256) {
            int n = i / 4, c = i % 4;
            *(unsigned*)&wtb[n * K2PAD + HIDDEN + 2 * c] = 0;
        }
        // fused epilogue-1: h tile from agg + tpb(self), then zero agg tile
        for (int i = t; i < 64 * 16; i += 256) {
            int r = i >> 4, c = i & 15;            // c = float4 index
            int n_raw = n0 + r;
            int n = (n_raw < N_NODES) ? n_raw : N_NODES - 1;
            float4 va = ((const float4*)agg)[n * 16 + c];
            uint2 ut = *(const uint2*)&tpb[n * 64 + c * 4];
            float di = dsv[r];
            float s0 = b2f((ushort_t)(ut.x & 0xffff));
            float s1 = b2f((ushort_t)(ut.x >> 16));
            float s2 = b2f((ushort_t)(ut.y & 0xffff));
            float s3 = b2f((ushort_t)(ut.y >> 16));
            float h0 = fmaxf(fmaf(va.x + s0, di, bsv[c * 4 + 0]), 0.f);
            float h1 = fmaxf(fmaf(va.y + s1, di, bsv[c * 4 + 1]), 0.f);
            float h2 = fmaxf(fmaf(va.z + s2, di, bsv[c * 4 + 2]), 0.f);
            float h3 = fmaxf(fmaf(va.w + s3, di, bsv[c * 4 + 3]), 0.f);
            *(uint2*)&hsb[r * K2PAD + 4 * c] = make_uint2(pack2(h0, h1), pack2(h2, h3));
            if (n_raw < N_NODES)
                ((float4*)agg)[n * 16 + c] = make_float4(0.f, 0.f, 0.f, 0.f);
        }
        for (int i = t; i < 64 * 4; i += 256) {    // pad [64,72)
            int r = i / 4, c = i % 4;
            *(unsigned*)&hsb[r * K2PAD + HIDDEN + 2 * c] = 0;
        }
    }
    __syncthreads();
    int w = t >> 6, lane = t & 63;
    int quad = lane >> 4, l16 = lane & 15;
    f32x4 acc[4] = {{0,0,0,0},{0,0,0,0},{0,0,0,0},{0,0,0,0}};
#pragma unroll
    for (int kc = 0; kc < 2; ++kc) {
        bf16x8 a = *(const bf16x8*)&hsb[(w * 16 + l16) * K2PAD + kc * 32 + quad * 8];
#pragma unroll
        for (int nt = 0; nt < 4; ++nt) {
            bf16x8 b = *(const bf16x8*)&wtb[(nt * 16 + l16) * K2PAD + kc * 32 + quad * 8];
            acc[nt] = __builtin_amdgcn_mfma_f32_16x16x32_bf16(a, b, acc[nt], 0, 0, 0);
        }
    }
#pragma unroll
    for (int r = 0; r < 4; ++r) {
        int nl = w * 16 + quad * 4 + r;
        int node = n0 + nl;
        if (node < N_NODES) {
            float di = dsv[nl];
#pragma unroll
            for (int nt = 0; nt < 4; ++nt)
                tpb[node * 64 + nt * 16 + l16] = f2b(acc[nt][r] * di);
        }
    }
}

// ======== edge-parallel segmented reduce, contiguous 128-edge waves =========
// dst_sorted sorted => each wave's interior segments are exclusively owned:
// plain 256B stores. Only the first and final flush of a wave use atomicAdd.
__global__ __launch_bounds__(256, 4) void edge_seg_kernel(const int* __restrict__ csr_src,
                                                          const int* __restrict__ dst_sorted,
                                                          const ushort_t* __restrict__ tpb,
                                                          float* __restrict__ agg) {
    int lane = threadIdx.x & 63;
    int wid  = (blockIdx.x * 256 + threadIdx.x) >> 6;
    if (wid >= NWAVE) return;
    int e0 = wid * EPW;

    // 4 coalesced 256B index loads cover the wave's 128 edges
    int sv0 = csr_src[e0 + lane],      sv1 = csr_src[e0 + 64 + lane];
    int dv0 = dst_sorted[e0 + lane],   dv1 = dst_sorted[e0 + 64 + lane];

    float acc = 0.0f;
    int dprev = __builtin_amdgcn_readlane(dv0, 0);
    int nflush = 0;
#pragma unroll
    for (int j = 0; j < 8; ++j) {
        int svj = (j < 4) ? sv0 : sv1;
        int dvj = (j < 4) ? dv0 : dv1;
        int base = (j * 16) & 63;
        int ss[16], dd[16];
#pragma unroll
        for (int k = 0; k < 16; ++k) {
            ss[k] = __builtin_amdgcn_readlane(svj, base + k);
            dd[k] = __builtin_amdgcn_readlane(dvj, base + k);
        }
        float vv[16];
#pragma unroll
        for (int k = 0; k < 16; ++k) vv[k] = b2f(tpb[ss[k] * 64 + lane]);
#pragma unroll
        for (int k = 0; k < 16; ++k) {
            if (dd[k] != dprev) {                 // wave-uniform branch
                if (nflush == 0) atomicAdd(&agg[dprev * 64 + lane], acc);
                else             agg[dprev * 64 + lane] = acc;   // exclusive owner
                ++nflush;
                acc = 0.0f;
                dprev = dd[k];
            }
            acc += vv[k];
        }
    }
    atomicAdd(&agg[dprev * 64 + lane], acc);      // final segment may be shared
}

// ---- layer-2 epilogue + pool: one BLOCK per graph (4 waves), no atomics ----
__global__ __launch_bounds__(256) void gpool_kernel(const float* __restrict__ agg,
                                                    const ushort_t* __restrict__ tpb,
                                                    const float* __restrict__ dinv,
                                                    const float* __restrict__ bias,
                                                    const int* __restrict__ gstart,
                                                    float* __restrict__ sums,
                                                    float* __restrict__ gcount) {
    __shared__ float red[4][64];
    int lane = threadIdx.x & 63;
    int w = threadIdx.x >> 6;
    int g = blockIdx.x;                      // 512 blocks
    int s = gstart[g], e = gstart[g + 1];
    float b = bias[lane];
    float acc = 0.0f;
    for (int n = s + w; n < e; n += 4) {
        int idx = n * 64 + lane;
        acc += fmaxf(fmaf(agg[idx] + b2f(tpb[idx]), dinv[n], b), 0.0f);
    }
    red[w][lane] = acc;
    __syncthreads();
    if (threadIdx.x < 64) {
        float tot = red[0][lane] + red[1][lane] + red[2][lane] + red[3][lane];
        sums[g * 64 + lane] = tot;
        if (lane == 0) gcount[g] = (float)(e - s);
    }
}

// ---- head: out = (sums/counts) @ Wout + bout -------------------------------
__global__ __launch_bounds__(256) void out_kernel(const float* __restrict__ sums,
                                                  const float* __restrict__ gcount,
                                                  const float* __restrict__ Wout,
                                                  const float* __restrict__ bout,
                                                  float* __restrict__ out) {
    int idx = blockIdx.x * 256 + threadIdx.x;
    if (idx >= NUM_GRAPHS * N_CLASSES) return;
    int g = idx / N_CLASSES, c = idx % N_CLASSES;
    float inv_cnt = 1.0f / fmaxf(gcount[g], 1.0f);
    float acc = 0.0f;
#pragma unroll
    for (int k = 0; k < HIDDEN; ++k)
        acc += sums[g * HIDDEN + k] * Wout[k * N_CLASSES + c];
    out[idx] = acc * inv_cnt + bout[c];
}

extern "C" void kernel_launch(void* const* d_in, const int* in_sizes, int n_in,
                              void* d_out, int out_size, void* d_ws, size_t ws_size,
                              hipStream_t stream) {
    const float* x     = (const float*)d_in[0];
    const int*   ei    = (const int*)d_in[1];
    const int*   batch = (const int*)d_in[2];
    const float* W1    = (const float*)d_in[3];
    const float* b1    = (const float*)d_in[4];
    const float* W2    = (const float*)d_in[5];
    const float* b2    = (const float*)d_in[6];
    const float* Wout  = (const float*)d_in[7];
    const float* bout  = (const float*)d_in[8];
    float* out = (float*)d_out;

    const int* src = ei;
    const int* dst = ei + N_EDGES;

    // -------- workspace layout (~48 MB) --------
    char* p = (char*)d_ws;
    int*      row_ptr   = (int*)p;      p += (NP_PAD + 256) * sizeof(int);
    int*      cnt       = (int*)p;      p += NP_PAD * sizeof(int);   // histogram
    int*      cursor    = (int*)p;      p += NP_PAD * sizeof(int);   // scatter cursor
    int*      partials  = (int*)p;      p += 256 * sizeof(int);
    int*      gstart    = (int*)p;      p += (NUM_GRAPHS + 64) * sizeof(int);
    int*      csr_src   = (int*)p;      p += (size_t)E_PAD * sizeof(int);
    int*      dst_sorted= (int*)p;      p += (size_t)E_PAD * sizeof(int);
    float*    dinv      = (float*)p;    p += NP_PAD * sizeof(float);
    ushort_t* tpb       = (ushort_t*)p; p += (size_t)N_NODES * HIDDEN * sizeof(ushort_t);
    float*    agg       = (float*)p;    p += (size_t)(N_NODES + 1) * HIDDEN * sizeof(float);
    float*    sums      = (float*)p;    p += NUM_GRAPHS * HIDDEN * sizeof(float);
    float*    gcount    = (float*)p;    p += NUM_GRAPHS * sizeof(float);

    const int NB_E  = (N_EDGES + 255) / 256;
    const int NB_MM = (N_NODES + 63) / 64;    // 1563 (last block guarded)

    // -------- CSR build + graph bounds --------
    hipMemsetAsync(cnt, 0, NP_PAD * sizeof(int), stream);
    hist_kernel<<<NB_E, 256, 0, stream>>>(dst, cnt);
    scan1_kernel<<<SCAN_BLKS, 256, 0, stream>>>(cnt, row_ptr, partials);
    scan2_kernel<<<1, 128, 0, stream>>>(partials);
    scan3_kernel<<<NP_PAD / 256 + 1, 256, 0, stream>>>(row_ptr, cnt, cursor, partials,
                                                       dst_sorted, csr_src, dinv);
    scatter_kernel<<<XCD * NB_E, 256, 0, stream>>>(src, dst, cursor, csr_src);
    gbounds_kernel<<<3, 256, 0, stream>>>(batch, gstart);

    hipMemsetAsync(agg, 0, (size_t)(N_NODES + 1) * HIDDEN * sizeof(float), stream);

    // -------- layer 1 --------
    mm1_kernel<<<NB_MM, 256, 0, stream>>>(x, W1, dinv, tpb);
    edge_seg_kernel<<<SEG_BLOCKS, 256, 0, stream>>>(csr_src, dst_sorted, tpb, agg);

    // -------- layer 2: mm2 fuses epilogue-1 (b1) + agg re-zero --------
    mm2_kernel<<<NB_MM, 256, 0, stream>>>(agg, tpb, W2, dinv, b1);
    edge_seg_kernel<<<SEG_BLOCKS, 256, 0, stream>>>(csr_src, dst_sorted, tpb, agg);
    gpool_kernel<<<NUM_GRAPHS, 256, 0, stream>>>(agg, tpb, dinv, b2, gstart,
                                                 sums, gcount);

    // -------- head --------
    out_kernel<<<(NUM_GRAPHS * N_CLASSES + 255) / 256, 256, 0, stream>>>(
        sums, gcount, Wout, bout, out);
}